// Round 13
// baseline (1651.525 us; speedup 1.0000x reference)
//
#include <hip/hip_runtime.h>
#include <hip/hip_bf16.h>

// Sizes
#define Dm    1024
#define Hn    16
#define KVH   4
#define DH    64
#define CHUNK 256
#define SDIM  128
#define MG    8
#define Bn    4
#define Tn    4096
#define TC    264            // MG + CHUNK
#define NSTEP 16
#define TD    4194304L       // Tn*Dm per batch

typedef __attribute__((ext_vector_type(8))) short short8;
typedef __attribute__((ext_vector_type(4))) float floatx4;
typedef __hip_bfloat16 bf16;

__device__ __forceinline__ void gl16(const void* g, void* l) {
    using GP = const __attribute__((address_space(1))) char*;
    using LP = __attribute__((address_space(3))) char*;
    __builtin_amdgcn_global_load_lds((GP)g, (LP)l, 16, 0, 0);
}
__device__ __forceinline__ float b2f(short s) {
    unsigned int u = ((unsigned int)(unsigned short)s) << 16;
    float f; __builtin_memcpy(&f, &u, 4); return f;
}
__device__ __forceinline__ short f2b(float f) {
    bf16 h = __float2bfloat16(f);
    short s; __builtin_memcpy(&s, &h, 2); return s;
}

// ---------------- utility kernels ----------------

__global__ __launch_bounds__(512) void vcopy_k(const float* __restrict__ s, float* __restrict__ d, int n) {
    int i = blockIdx.x * 512 + threadIdx.x;
    if (i < n) d[i] = s[i];
}

__global__ __launch_bounds__(256) void cvt_bf16_k(const float* __restrict__ s, bf16* __restrict__ d, int n4) {
    int i = blockIdx.x * 256 + threadIdx.x;
    if (i >= n4) return;
    float4 v = ((const float4*)s)[i];
    bf16* o = d + i * 4;
    o[0] = __float2bfloat16(v.x); o[1] = __float2bfloat16(v.y);
    o[2] = __float2bfloat16(v.z); o[3] = __float2bfloat16(v.w);
}

// WsiT[s][d] = bf16(Wsi[d][s])  (Wsi is [1024][128])
__global__ __launch_bounds__(256) void wsiT_k(const float* __restrict__ Wsi, bf16* __restrict__ WsiT) {
    int idx = blockIdx.x * 256 + threadIdx.x;     // 0..131071
    int s = idx >> 10, d = idx & 1023;
    WsiT[idx] = __float2bfloat16(Wsi[d * SDIM + s]);
}

// bfused[n] = wqkv[n] . bsi   (1536 outputs, K=1024)
__global__ __launch_bounds__(64) void bfused_k(const bf16* __restrict__ wqkv, const float* __restrict__ bsi,
                                               float* __restrict__ bfused) {
    int n = blockIdx.x * 64 + threadIdx.x;
    const bf16* wr = wqkv + (long)n * 1024;
    float a = 0.f;
    for (int k8 = 0; k8 < 128; ++k8) {
        short8 wv = *(const short8*)(wr + k8 * 8);
#pragma unroll
        for (int e = 0; e < 8; ++e) a += b2f(wv[e]) * bsi[k8 * 8 + e];
    }
    bfused[n] = a;
}

// group LN: grid (G*264, 4) x 256. bx -> (sl, r). r<8: gtok raw; else LN(x row of chunk c0+sl).
__global__ __launch_bounds__(256) void lng_k(const float* __restrict__ x, const float* __restrict__ gtok,
                                             const float* __restrict__ g, const float* __restrict__ be,
                                             bf16* __restrict__ lnxg, int c0) {
    int bx = blockIdx.x, b = blockIdx.y, tid = threadIdx.x;
    int sl = bx / 264, r = bx - sl * 264;
    bf16* orow = lnxg + (long)((sl * 4 + b) * 264 + r) * 1024 + tid * 4;
    if (r < MG) {
        float4 v = *(const float4*)(gtok + r * 1024 + tid * 4);
        orow[0] = __float2bfloat16(v.x); orow[1] = __float2bfloat16(v.y);
        orow[2] = __float2bfloat16(v.z); orow[3] = __float2bfloat16(v.w);
        return;
    }
    const float* row = x + (long)b * TD + ((long)(c0 + sl) * 256 + (r - MG)) * 1024;
    float4 v = *(const float4*)(row + tid * 4);
    float s = v.x + v.y + v.z + v.w;
    float q = v.x * v.x + v.y * v.y + v.z * v.z + v.w * v.w;
    for (int off = 32; off > 0; off >>= 1) { s += __shfl_down(s, off); q += __shfl_down(q, off); }
    __shared__ float red[10];
    int w = tid >> 6;
    if ((tid & 63) == 0) { red[w] = s; red[4 + w] = q; }
    __syncthreads();
    if (tid == 0) {
        float ts = red[0] + red[1] + red[2] + red[3];
        float tq = red[4] + red[5] + red[6] + red[7];
        float mean = ts * (1.f / Dm);
        float var = tq * (1.f / Dm) - mean * mean;
        red[8] = mean;
        red[9] = rsqrtf(var + 1e-5f);
    }
    __syncthreads();
    float mean = red[8], rstd = red[9];
    int d = tid * 4;
    float4 gv = *(const float4*)(g + d);
    float4 bv = *(const float4*)(be + d);
    orow[0] = __float2bfloat16((v.x - mean) * rstd * gv.x + bv.x);
    orow[1] = __float2bfloat16((v.y - mean) * rstd * gv.y + bv.y);
    orow[2] = __float2bfloat16((v.z - mean) * rstd * gv.z + bv.z);
    orow[3] = __float2bfloat16((v.w - mean) * rstd * gv.w + bv.w);
}

// ---------------- bf16 MFMA GEMM, 128x128 tile, BK=32 2-buffer, XCD-swizzled, bf16 out ----------------
// For the big hoisted QKV GEMM. Round-4-verified wave/fragment mapping.
__global__ __launch_bounds__(256) void gemm128(
    const bf16* __restrict__ A, const bf16* __restrict__ W,
    int M, int N, int K, bf16* __restrict__ Cb, int ldc)
{
    __shared__ short As[2][4096];
    __shared__ short Bs[2][4096];
    int tid = threadIdx.x;
    int w = tid >> 6, l = tid & 63;
    int wr = w >> 1, wc = w & 1;

    // bijective XCD swizzle (m204): contiguous chunk of blocks per XCD
    int nbx = gridDim.x;
    int nwg = nbx * gridDim.y;
    int orig = blockIdx.y * nbx + blockIdx.x;
    int q = nwg >> 3, r8 = nwg & 7, xcd = orig & 7;
    int base = (xcd < r8) ? xcd * (q + 1) : r8 * (q + 1) + (xcd - r8) * q;
    int nid = base + (orig >> 3);
    int by = nid / nbx, bx = nid - by * nbx;
    int m0 = by << 7, n0 = bx << 7;

    int r0 = w * 16 + (l >> 2);
    int kc = (l & 3) << 3;
    const bf16* pA0 = A + (long)(m0 + r0) * K + kc;
    const bf16* pA1 = pA0 + (long)64 * K;
    const bf16* pW0 = W + (long)(n0 + r0) * K + kc;
    const bf16* pW1 = pW0 + (long)64 * K;
    int lofs = w * 1024 + l * 16;
    char* cA = (char*)As;
    char* cB = (char*)Bs;

    floatx4 acc[4][4];
#pragma unroll
    for (int i = 0; i < 4; ++i)
#pragma unroll
        for (int j = 0; j < 4; ++j) acc[i][j] = (floatx4){0.f, 0.f, 0.f, 0.f};

    int arow = wr * 64 + (l & 15);
    int brow = wc * 64 + (l & 15);
    int acol = (l >> 4) << 3;
    int nk = K >> 5;

#define STAGE(t)                                            \
    {                                                       \
        int kt_ = (t) << 5;                                 \
        int bo_ = ((t) & 1) * 8192;                         \
        gl16(pA0 + kt_, cA + bo_ + lofs);                   \
        gl16(pA1 + kt_, cA + bo_ + 4096 + lofs);            \
        gl16(pW0 + kt_, cB + bo_ + lofs);                   \
        gl16(pW1 + kt_, cB + bo_ + 4096 + lofs);            \
    }

    STAGE(0)
    for (int i = 0; i < nk; ++i) {
        if (i + 1 < nk) {
            STAGE(i + 1)
            asm volatile("s_waitcnt vmcnt(4)" ::: "memory");
        } else {
            asm volatile("s_waitcnt vmcnt(0)" ::: "memory");
        }
        __builtin_amdgcn_s_barrier();
        __builtin_amdgcn_sched_barrier(0);
        const short* Ab = As[i & 1];
        const short* Bb = Bs[i & 1];
        short8 a[4], b[4];
#pragma unroll
        for (int t = 0; t < 4; ++t) {
            a[t] = *(const short8*)&Ab[(arow + t * 16) * 32 + acol];
            b[t] = *(const short8*)&Bb[(brow + t * 16) * 32 + acol];
        }
#pragma unroll
        for (int ii = 0; ii < 4; ++ii)
#pragma unroll
            for (int jj = 0; jj < 4; ++jj)
                acc[ii][jj] = __builtin_amdgcn_mfma_f32_16x16x32_bf16(a[ii], b[jj], acc[ii][jj], 0, 0, 0);
        __builtin_amdgcn_sched_barrier(0);
        __builtin_amdgcn_s_barrier();
    }
#undef STAGE

    int crow0 = m0 + wr * 64 + ((l >> 4) << 2);
    int ccol0 = n0 + wc * 64 + (l & 15);
#pragma unroll
    for (int i = 0; i < 4; ++i)
#pragma unroll
        for (int rr = 0; rr < 4; ++rr) {
            int m = crow0 + i * 16 + rr;
            if (m >= M) continue;
            bf16* crow = Cb + (long)m * ldc;
#pragma unroll
            for (int j = 0; j < 4; ++j)
                crow[ccol0 + j * 16] = __float2bfloat16(acc[i][j][rr]);
        }
}

// ---------------- bf16 MFMA GEMM, 64xBN tile, BK=64 phases, 2-buffer, optional split-K ----------------
template<int BN>
__global__ __launch_bounds__(256) void gemm64(
    const bf16* __restrict__ A, const bf16* __restrict__ W,
    int M, int N, int K, int kspan,
    bf16* __restrict__ Cb, int ldc, const float* __restrict__ bias, int gelu,
    float* __restrict__ Cpart, long partMN)
{
    constexpr int NSEG = 4 + BN / 16;     // 1KB segments per 32-k half
    constexpr int SEGW = NSEG / 4;        // segments per wave per half
    constexpr int FC   = BN / 64;
    constexpr int WN   = BN / 4;
    constexpr int HALFB = NSEG * 1024;    // bytes per 32-k half
    constexpr int PHB   = 2 * HALFB;      // bytes per 64-k phase buffer
    __shared__ short S[PHB];              // two phase buffers

    int tid = threadIdx.x;
    int w = tid >> 6, l = tid & 63;
    int m0 = blockIdx.y << 6, n0 = blockIdx.x * BN;
    long kb = (long)blockIdx.z * kspan;

    const bf16* gp[SEGW];
    int so[SEGW];
#pragma unroll
    for (int si = 0; si < SEGW; ++si) {
        int s = w + si * 4;
        const bf16* base = (s < 4) ? (A + (long)(m0 + s * 16 + (l >> 2)) * K)
                                   : (W + (long)(n0 + (s - 4) * 16 + (l >> 2)) * K);
        gp[si] = base + ((l & 3) << 3) + kb;
        so[si] = s * 1024 + l * 16;
    }
    char* cS = (char*)S;

    floatx4 acc[4][FC];
#pragma unroll
    for (int t = 0; t < 4; ++t)
#pragma unroll
        for (int u = 0; u < FC; ++u) acc[t][u] = (floatx4){0.f, 0.f, 0.f, 0.f};

    int arow = l & 15;
    int acol = (l >> 4) << 3;
    int np = kspan >> 6;

#define STAGE(p)                                                         \
    {                                                                    \
        int kt_ = (p) << 6;                                              \
        char* b_ = cS + ((p) & 1) * PHB;                                 \
        _Pragma("unroll")                                                \
        for (int si = 0; si < SEGW; ++si) {                              \
            gl16(gp[si] + kt_, b_ + so[si]);                             \
            gl16(gp[si] + kt_ + 32, b_ + HALFB + so[si]);                \
        }                                                                \
    }

    STAGE(0)
    for (int p = 0; p < np; ++p) {
        if (p + 1 < np) {
            STAGE(p + 1)
            if constexpr (SEGW == 2) asm volatile("s_waitcnt vmcnt(4)" ::: "memory");
            else                     asm volatile("s_waitcnt vmcnt(6)" ::: "memory");
        } else {
            asm volatile("s_waitcnt vmcnt(0)" ::: "memory");
        }
        __builtin_amdgcn_s_barrier();
        __builtin_amdgcn_sched_barrier(0);
        const short* buf = S + (p & 1) * (PHB / 2);
#pragma unroll
        for (int kh = 0; kh < 2; ++kh) {
            const short* hb = buf + kh * (HALFB / 2);
            short8 a[4], b[FC];
#pragma unroll
            for (int t = 0; t < 4; ++t)
                a[t] = *(const short8*)&hb[(t * 16 + arow) * 32 + acol];
#pragma unroll
            for (int u = 0; u < FC; ++u)
                b[u] = *(const short8*)&hb[2048 + (w * WN + u * 16 + arow) * 32 + acol];
#pragma unroll
            for (int t = 0; t < 4; ++t)
#pragma unroll
                for (int u = 0; u < FC; ++u)
                    acc[t][u] = __builtin_amdgcn_mfma_f32_16x16x32_bf16(a[t], b[u], acc[t][u], 0, 0, 0);
        }
        __builtin_amdgcn_sched_barrier(0);
        __builtin_amdgcn_s_barrier();
    }
#undef STAGE

    int crow0 = m0 + ((l >> 4) << 2);
    int ccol0 = n0 + w * WN + (l & 15);
    if (Cpart) {
        float* pp = Cpart + (long)blockIdx.z * partMN;
#pragma unroll
        for (int t = 0; t < 4; ++t)
#pragma unroll
            for (int rr = 0; rr < 4; ++rr) {
                int m = crow0 + t * 16 + rr;
                if (m >= M) continue;
#pragma unroll
                for (int u = 0; u < FC; ++u)
                    pp[(long)m * N + ccol0 + u * 16] = acc[t][u][rr];
            }
    } else {
#pragma unroll
        for (int t = 0; t < 4; ++t)
#pragma unroll
            for (int rr = 0; rr < 4; ++rr) {
                int m = crow0 + t * 16 + rr;
                if (m >= M) continue;
                bf16* crow = Cb + (long)m * ldc;
#pragma unroll
                for (int u = 0; u < FC; ++u) {
                    int n = ccol0 + u * 16;
                    float v = acc[t][u][rr];
                    if (bias) v += bias[n];
                    if (gelu) v = 0.5f * v * (1.f + erff(v * 0.70710678118654752f));
                    crow[n] = __float2bfloat16(v);
                }
            }
    }
}

// ---------------- fused Wo-reduce + residual + FFN LayerNorm + next-state init ----------------
__global__ __launch_bounds__(256) void reduce_ln_k(const float* __restrict__ part,
                                                   const float* __restrict__ bo,
                                                   const float* __restrict__ x,
                                                   float* __restrict__ out, long roff,
                                                   const float* __restrict__ g,
                                                   const float* __restrict__ be,
                                                   bf16* __restrict__ t_ln,
                                                   const float* __restrict__ bsp,
                                                   float* __restrict__ stn) {
    int m = blockIdx.x;                  // 0..1023
    int b = m >> 8, r = m & 255;
    int tid = threadIdx.x;
    if (r == 0 && tid < SDIM) stn[b * SDIM + tid] = bsp[tid];   // init next state to bias
    long ro = (long)b * TD + (roff + r) * 1024L + tid * 4;
    int pi = m * 256 + tid;
    float4 s  = ((const float4*)part)[pi];
    float4 p2 = ((const float4*)(part + 1048576))[pi];
    float4 bv = ((const float4*)bo)[tid];
    float4 rv = *(const float4*)(x + ro);
    float c0 = s.x + p2.x + bv.x + rv.x;
    float c1 = s.y + p2.y + bv.y + rv.y;
    float c2 = s.z + p2.z + bv.z + rv.z;
    float c3 = s.w + p2.w + bv.w + rv.w;
    *(float4*)(out + ro) = make_float4(c0, c1, c2, c3);
    float sum = c0 + c1 + c2 + c3;
    float sq  = c0 * c0 + c1 * c1 + c2 * c2 + c3 * c3;
    for (int off = 32; off > 0; off >>= 1) { sum += __shfl_down(sum, off); sq += __shfl_down(sq, off); }
    __shared__ float red[10];
    int w = tid >> 6;
    if ((tid & 63) == 0) { red[w] = sum; red[4 + w] = sq; }
    __syncthreads();
    if (tid == 0) {
        float ts = red[0] + red[1] + red[2] + red[3];
        float tq = red[4] + red[5] + red[6] + red[7];
        float mean = ts * (1.f / Dm);
        float var = tq * (1.f / Dm) - mean * mean;
        red[8] = mean;
        red[9] = rsqrtf(var + 1e-5f);
    }
    __syncthreads();
    float mean = red[8], rstd = red[9];
    float4 gv = ((const float4*)g)[tid];
    float4 bev = ((const float4*)be)[tid];
    bf16* orow = t_ln + (long)(b * CHUNK + r) * Dm + tid * 4;
    orow[0] = __float2bfloat16((c0 - mean) * rstd * gv.x + bev.x);
    orow[1] = __float2bfloat16((c1 - mean) * rstd * gv.y + bev.y);
    orow[2] = __float2bfloat16((c2 - mean) * rstd * gv.z + bev.z);
    orow[3] = __float2bfloat16((c3 - mean) * rstd * gv.w + bev.w);
}

// ---------------- fused FFN2-reduce + residual + state partial-dot (atomic) ----------------
// grid (b=4, rg=32) x 256; 8 rows each. out = part0+part1+b2+c_pre;
// then pss[ss] = cs . Wsp[ss]; atomicAdd(stn, pss/CHUNK).
__global__ __launch_bounds__(256) void reduce_colpart_k(const float* __restrict__ part,
                                                        const float* __restrict__ bias,
                                                        float* __restrict__ out, long roff,
                                                        const float* __restrict__ Wsp,
                                                        float* __restrict__ stn) {
    int b = blockIdx.x, rg = blockIdx.y, tid = threadIdx.x;
    __shared__ float csm[1024];
    __shared__ float pss[128];
    float4 bv = ((const float4*)bias)[tid];
    float4 cs = make_float4(0.f, 0.f, 0.f, 0.f);
#pragma unroll
    for (int r8 = 0; r8 < 8; ++r8) {
        int r = rg * 8 + r8;
        int pi = (b * 256 + r) * 256 + tid;
        float4 s  = ((const float4*)part)[pi];
        float4 p2 = ((const float4*)(part + 1048576))[pi];
        long ro = (long)b * TD + (roff + r) * 1024L + tid * 4;
        float4 rv = *(const float4*)(out + ro);
        float4 v = make_float4(s.x + p2.x + bv.x + rv.x, s.y + p2.y + bv.y + rv.y,
                               s.z + p2.z + bv.z + rv.z, s.w + p2.w + bv.w + rv.w);
        *(float4*)(out + ro) = v;
        cs.x += v.x; cs.y += v.y; cs.z += v.z; cs.w += v.w;
    }
    csm[tid * 4 + 0] = cs.x; csm[tid * 4 + 1] = cs.y;
    csm[tid * 4 + 2] = cs.z; csm[tid * 4 + 3] = cs.w;
    __syncthreads();
    int w = tid >> 6, l = tid & 63;
#pragma unroll 4
    for (int i = 0; i < 32; ++i) {
        int ss = w * 32 + i;
        const float* wr = Wsp + (long)ss * Dm + l * 16;
        float p = 0.f;
#pragma unroll
        for (int t = 0; t < 16; ++t) p += csm[l * 16 + t] * wr[t];
        for (int off = 32; off > 0; off >>= 1) p += __shfl_down(p, off);
        if (l == 0) pss[ss] = p;
    }
    __syncthreads();
    if (tid < SDIM) atomicAdd(stn + b * SDIM + tid, pss[tid] * (1.f / CHUNK));
}

// ---------------- attention: MFMA flash + in-block sib from st, 4 waves x 16 queries ----------------
__global__ __launch_bounds__(256) void attn_mfma_k(const bf16* __restrict__ qkv,
                                                   const float* __restrict__ st,
                                                   const bf16* __restrict__ Wf,
                                                   const float* __restrict__ bfused,
                                                   bf16* __restrict__ o_mat) {
    int qc = blockIdx.x, head = blockIdx.y, b = blockIdx.z;
    int kvh = head >> 2;
    int tid = threadIdx.x, w = tid >> 6, l = tid & 63;
    int m16 = l & 15, h4 = l >> 4;

    __shared__ short Qs[64][64];
    __shared__ short Ks[64][64];
    __shared__ short Vt[64][64];           // [dim][key]
    __shared__ short Ps[4][16][64];        // per-wave P tile [q][key]
    __shared__ float sq[64], sk[64], sv[64];

    const long rowq0 = (long)b * TC + MG + qc * 64;
    const bf16* kbase = qkv + ((long)b * TC) * 1536 + 1024 + kvh * DH;
    const bf16* vbase = kbase + 256;

    // in-block sib slices: 192 threads each compute one K=128 dot
    if (tid < 192) {
        int which = tid >> 6, nn = tid & 63;
        int n = (which == 0) ? head * 64 + nn
              : (which == 1) ? 1024 + kvh * 64 + nn
                             : 1280 + kvh * 64 + nn;
        const bf16* wr = Wf + (long)n * SDIM;
        const float* sr = st + b * SDIM;
        float a = bfused[n];
#pragma unroll
        for (int k8 = 0; k8 < 16; ++k8) {
            short8 wv = *(const short8*)(wr + k8 * 8);
#pragma unroll
            for (int e = 0; e < 8; ++e) a += sr[k8 * 8 + e] * b2f(wv[e]);
        }
        if (which == 0) sq[nn] = a; else if (which == 1) sk[nn] = a; else sv[nn] = a;
    }
    __syncthreads();

    // stage Q with sib add (all Q rows are chunk tokens)
#pragma unroll
    for (int p = 0; p < 2; ++p) {
        int rr = p * 32 + (tid >> 3);
        int c0 = (tid & 7) * 8;
        short8 v = *(const short8*)(qkv + (rowq0 + rr) * 1536 + head * DH + c0);
        short8 o;
#pragma unroll
        for (int e = 0; e < 8; ++e) o[e] = f2b(b2f(v[e]) + sq[c0 + e]);
        *(short8*)&Qs[rr][c0] = o;
    }

    float a_m[4] = {-1e30f, -1e30f, -1e30f, -1e30f};
    float a_l[4] = {0.f, 0.f, 0.f, 0.f};
    floatx4 acc_o[4];
#pragma unroll
    for (int dt = 0; dt < 4; ++dt) acc_o[dt] = (floatx4){0.f, 0.f, 0.f, 0.f};
    short8 aq[2];

    int qtok0 = MG + qc * 64 + w * 16 + h4 * 4;
    int ntiles = qc + 2;

    for (int t = 0; t < ntiles; ++t) {
        int jt = t * 64;
        // stage K with conditional sib add (rows >= MG only)
#pragma unroll
        for (int p = 0; p < 2; ++p) {
            int rr = p * 32 + (tid >> 3);
            int c0 = (tid & 7) * 8;
            int gk = min(jt + rr, TC - 1);
            short8 v = *(const short8*)(kbase + (long)gk * 1536 + c0);
            short8 o;
            if (gk >= MG) {
#pragma unroll
                for (int e = 0; e < 8; ++e) o[e] = f2b(b2f(v[e]) + sk[c0 + e]);
            } else o = v;
            *(short8*)&Ks[rr][c0] = o;
        }
        // stage V transposed with conditional sib add
#pragma unroll
        for (int p = 0; p < 2; ++p) {
            int cg = p * 4 + w;
            int gk = min(jt + l, TC - 1);
            short8 vv = *(const short8*)(vbase + (long)gk * 1536 + cg * 8);
            if (gk >= MG) {
#pragma unroll
                for (int e = 0; e < 8; ++e) vv[e] = f2b(b2f(vv[e]) + sv[cg * 8 + e]);
            }
#pragma unroll
            for (int e = 0; e < 8; ++e) Vt[cg * 8 + e][l] = vv[e];
        }
        __syncthreads();
        if (t == 0) {
            aq[0] = *(const short8*)&Qs[w * 16 + m16][h4 * 8];
            aq[1] = *(const short8*)&Qs[w * 16 + m16][32 + h4 * 8];
        }
        floatx4 s[4];
#pragma unroll
        for (int st_ = 0; st_ < 4; ++st_) {
            s[st_] = (floatx4){0.f, 0.f, 0.f, 0.f};
#pragma unroll
            for (int c = 0; c < 2; ++c) {
                short8 kf = *(const short8*)&Ks[st_ * 16 + m16][c * 32 + h4 * 8];
                s[st_] = __builtin_amdgcn_mfma_f32_16x16x32_bf16(aq[c], kf, s[st_], 0, 0, 0);
            }
        }
#pragma unroll
        for (int st_ = 0; st_ < 4; ++st_) {
            int keyg = jt + st_ * 16 + m16;
#pragma unroll
            for (int r = 0; r < 4; ++r) {
                float v = s[st_][r] * 0.125f;
                s[st_][r] = (keyg > qtok0 + r) ? -1e30f : v;
            }
        }
#pragma unroll
        for (int r = 0; r < 4; ++r) {
            float tm = fmaxf(fmaxf(s[0][r], s[1][r]), fmaxf(s[2][r], s[3][r]));
            tm = fmaxf(tm, __shfl_xor(tm, 1));
            tm = fmaxf(tm, __shfl_xor(tm, 2));
            tm = fmaxf(tm, __shfl_xor(tm, 4));
            tm = fmaxf(tm, __shfl_xor(tm, 8));
            float mn = fmaxf(a_m[r], tm);
            float rs = __expf(a_m[r] - mn);
            a_m[r] = mn;
            float ps = 0.f;
#pragma unroll
            for (int st_ = 0; st_ < 4; ++st_) {
                float p = __expf(s[st_][r] - mn);
                s[st_][r] = p;
                ps += p;
            }
            ps += __shfl_xor(ps, 1); ps += __shfl_xor(ps, 2);
            ps += __shfl_xor(ps, 4); ps += __shfl_xor(ps, 8);
            a_l[r] = a_l[r] * rs + ps;
#pragma unroll
            for (int dt = 0; dt < 4; ++dt) acc_o[dt][r] *= rs;
#pragma unroll
            for (int st_ = 0; st_ < 4; ++st_) {
                Ps[w][h4 * 4 + r][st_ * 16 + m16] = f2b(s[st_][r]);
            }
        }
#pragma unroll
        for (int c = 0; c < 2; ++c) {
            short8 ap = *(const short8*)&Ps[w][m16][c * 32 + h4 * 8];
#pragma unroll
            for (int dt = 0; dt < 4; ++dt) {
                short8 vf = *(const short8*)&Vt[dt * 16 + m16][c * 32 + h4 * 8];
                acc_o[dt] = __builtin_amdgcn_mfma_f32_16x16x32_bf16(ap, vf, acc_o[dt], 0, 0, 0);
            }
        }
        __syncthreads();
    }

#pragma unroll
    for (int r = 0; r < 4; ++r) {
        float inv = 1.f / a_l[r];
        long row = (long)b * CHUNK + qc * 64 + w * 16 + h4 * 4 + r;
#pragma unroll
        for (int dt = 0; dt < 4; ++dt)
            o_mat[row * Dm + head * DH + dt * 16 + m16] = __float2bfloat16(acc_o[dt][r] * inv);
    }
}

// ---------------- orchestration ----------------

extern "C" void kernel_launch(void* const* d_in, const int* in_sizes, int n_in,
                              void* d_out, int out_size, void* d_ws, size_t ws_size,
                              hipStream_t stream) {
    const float* x     = (const float*)d_in[0];
    const float* state = (const float*)d_in[1];
    const float* Wq    = (const float*)d_in[2];
    const float* Wk    = (const float*)d_in[3];
    const float* Wv    = (const float*)d_in[4];
    const float* Wo    = (const float*)d_in[5];
    const float* bo    = (const float*)d_in[6];
    const float* lag   = (const float*)d_in[7];
    const float* lab   = (const float*)d_in[8];
    const float* lfg   = (const float*)d_in[9];
    const float* lfb   = (const float*)d_in[10];
    const float* W1    = (const float*)d_in[11];
    const float* b1    = (const float*)d_in[12];
    const float* W2    = (const float*)d_in[13];
    const float* b2    = (const float*)d_in[14];
    const float* Wsp   = (const float*)d_in[15];
    const float* bsp   = (const float*)d_in[16];
    const float* Wsi   = (const float*)d_in[17];
    const float* bsi   = (const float*)d_in[18];
    const float* gtok  = (const float*)d_in[19];

    float* out = (float*)d_out;
    char*  wsb = (char*)d_ws;

    // QKV hoist group size: all 16 steps if workspace allows (~110MB), else 4
    const long stepQ = 4L * TC * 1536;                 // bf16 elems per step slot
    const int G = (ws_size >= (size_t)115000000) ? 16 : 4;

    // workspace layout (bytes)
    bf16* wqkv   = (bf16*)(wsb);                      // 1536x1024   3,145,728
    bf16* wo     = (bf16*)(wsb + 3145728);            // 1024x1024   2,097,152
    bf16* w1     = (bf16*)(wsb + 5242880);            // 4096x1024   8,388,608
    bf16* w2     = (bf16*)(wsb + 13631488);           // 1024x4096   8,388,608
    bf16* Wfused = (bf16*)(wsb + 22020096);           // 1536x128      393,216
    bf16* WsiT   = (bf16*)(wsb + 22413312);           // 128x1024      262,144 (setup-transient)
    float* st1   = (float*)(wsb + 22413312);           // aliases WsiT after setup
    float* bfused= (float*)(wsb + 22675456);          // 1536            6,144
    float* st0   = (float*)(wsb + 22681600);          // 512             2,048
    bf16* qkvg   = (bf16*)(wsb + 22683648);           // G slots x 3,244,032 B
    char* R2     = wsb + 22683648 + (size_t)G * 3244032;
    // R2: lnxg (G*1056*1024*2 B, setup-transient) ∪ loop {u, part, scrB}
    bf16* lnxg   = (bf16*)R2;
    bf16* u      = (bf16*)R2;                          // 1024x4096 bf16 = 8,388,608
    float* part  = (float*)(R2 + 8388608);             // 2x1024x1024 f32 = 8,388,608
    char* scrB   = R2 + 16777216;                      // o_mat ∪ t_ln (2,097,152)
    bf16* o_mat  = (bf16*)scrB;
    bf16* t_ln   = (bf16*)scrB;
    // G=16 total ≈ 109.2MB ; G=4 total ≈ 54.5MB

    // ---- setup ----
    vcopy_k<<<1, 512, 0, stream>>>(state, st0, 512);
    cvt_bf16_k<<<1024, 256, 0, stream>>>(Wq, wqkv,            262144);
    cvt_bf16_k<<< 256, 256, 0, stream>>>(Wk, wqkv + 1048576,   65536);
    cvt_bf16_k<<< 256, 256, 0, stream>>>(Wv, wqkv + 1310720,   65536);
    cvt_bf16_k<<<1024, 256, 0, stream>>>(Wo, wo,              262144);
    cvt_bf16_k<<<4096, 256, 0, stream>>>(W1, w1,             1048576);
    cvt_bf16_k<<<4096, 256, 0, stream>>>(W2, w2,             1048576);
    wsiT_k<<<512, 256, 0, stream>>>(Wsi, WsiT);
    // Wfused = wqkv @ WsiT^T : M=1536, N=128, K=1024  (before st1 aliases WsiT)
    gemm64<64><<<dim3(2, 24, 1), 256, 0, stream>>>(
        wqkv, WsiT, 1536, 128, 1024, 1024,
        Wfused, 128, nullptr, 0, nullptr, 0L);
    bfused_k<<<24, 64, 0, stream>>>(wqkv, bsi, bfused);

    float* stbuf[2] = { st0, st1 };
    for (int s = 0; s < NSTEP; ++s) {
        long roff = (long)s * CHUNK;
        if (s % G == 0) {
            // LN(x)+gtok rows for G steps, then one QKV GEMM: M = G*1056 (multiple of 128)
            lng_k<<<dim3(G * 264, 4), 256, 0, stream>>>(x, gtok, lag, lab, lnxg, s);
            gemm128<<<dim3(12, G * 1056 / 128), 256, 0, stream>>>(
                lnxg, wqkv, G * 1056, 1536, 1024, qkvg, 1536);
        }
        const bf16* qkv_s = qkvg + (long)(s % G) * stepQ;
        const float* stc = stbuf[s & 1];
        float* stn = stbuf[(s + 1) & 1];
        // attention with in-block sib correction (reads current state)
        attn_mfma_k<<<dim3(4, 16, 4), 256, 0, stream>>>(qkv_s, stc, Wfused, bfused, o_mat);
        // Wo split-K (KS=2) -> part; fused reduce(+bo,+x) + FFN LN + init next state
        gemm64<64><<<dim3(16, 16, 2), 256, 0, stream>>>(
            o_mat, wo, Bn * CHUNK, 1024, 1024, 512,
            nullptr, 0, nullptr, 0, part, 1048576L);
        reduce_ln_k<<<1024, 256, 0, stream>>>(part, bo, x, out, roff, lfg, lfb, t_ln, bsp, stn);
        // FFN1 + gelu -> u bf16
        gemm64<128><<<dim3(32, 16, 1), 256, 0, stream>>>(
            t_ln, w1, Bn * CHUNK, 4096, 1024, 1024,
            u, 4096, b1, 1, nullptr, 0L);
        // FFN2 split-K (KS=2) -> part; fused reduce(+b2,+c_pre) + state partial-dot (atomic)
        gemm64<64><<<dim3(16, 16, 2), 256, 0, stream>>>(
            u, w2, Bn * CHUNK, 1024, 4096, 2048,
            nullptr, 0, nullptr, 0, part, 1048576L);
        reduce_colpart_k<<<dim3(4, 32), 256, 0, stream>>>(part, b2, out, roff, Wsp, stn);
    }
    // after s=15, next state lives in stbuf[0]
    vcopy_k<<<1, 512, 0, stream>>>(stbuf[0], out + (long)Bn * Tn * Dm, 512);
}

// Round 14
// 1617.406 us; speedup vs baseline: 1.0211x; 1.0211x over previous
//
#include <hip/hip_runtime.h>
#include <hip/hip_bf16.h>

// Sizes
#define Dm    1024
#define Hn    16
#define KVH   4
#define DH    64
#define CHUNK 256
#define SDIM  128
#define MG    8
#define Bn    4
#define Tn    4096
#define TC    264            // MG + CHUNK
#define NSTEP 16
#define TD    4194304L       // Tn*Dm per batch

typedef __attribute__((ext_vector_type(8))) short short8;
typedef __attribute__((ext_vector_type(4))) float floatx4;
typedef __hip_bfloat16 bf16;

__device__ __forceinline__ void gl16(const void* g, void* l) {
    using GP = const __attribute__((address_space(1))) char*;
    using LP = __attribute__((address_space(3))) char*;
    __builtin_amdgcn_global_load_lds((GP)g, (LP)l, 16, 0, 0);
}
__device__ __forceinline__ float b2f(short s) {
    unsigned int u = ((unsigned int)(unsigned short)s) << 16;
    float f; __builtin_memcpy(&f, &u, 4); return f;
}
__device__ __forceinline__ short f2b(float f) {
    bf16 h = __float2bfloat16(f);
    short s; __builtin_memcpy(&s, &h, 2); return s;
}

// ---------------- utility kernels ----------------

__global__ __launch_bounds__(512) void vcopy_k(const float* __restrict__ s, float* __restrict__ d, int n) {
    int i = blockIdx.x * 512 + threadIdx.x;
    if (i < n) d[i] = s[i];
}

__global__ __launch_bounds__(256) void cvt_bf16_k(const float* __restrict__ s, bf16* __restrict__ d, int n4) {
    int i = blockIdx.x * 256 + threadIdx.x;
    if (i >= n4) return;
    float4 v = ((const float4*)s)[i];
    bf16* o = d + i * 4;
    o[0] = __float2bfloat16(v.x); o[1] = __float2bfloat16(v.y);
    o[2] = __float2bfloat16(v.z); o[3] = __float2bfloat16(v.w);
}

// WsiT[s][d] = bf16(Wsi[d][s])  (Wsi is [1024][128])
__global__ __launch_bounds__(256) void wsiT_k(const float* __restrict__ Wsi, bf16* __restrict__ WsiT) {
    int idx = blockIdx.x * 256 + threadIdx.x;     // 0..131071
    int s = idx >> 10, d = idx & 1023;
    WsiT[idx] = __float2bfloat16(Wsi[d * SDIM + s]);
}

// bfused[n] = wqkv[n] . bsi   (1536 outputs, K=1024)
__global__ __launch_bounds__(64) void bfused_k(const bf16* __restrict__ wqkv, const float* __restrict__ bsi,
                                               float* __restrict__ bfused) {
    int n = blockIdx.x * 64 + threadIdx.x;
    const bf16* wr = wqkv + (long)n * 1024;
    float a = 0.f;
    for (int k8 = 0; k8 < 128; ++k8) {
        short8 wv = *(const short8*)(wr + k8 * 8);
#pragma unroll
        for (int e = 0; e < 8; ++e) a += b2f(wv[e]) * bsi[k8 * 8 + e];
    }
    bfused[n] = a;
}

// group LN: grid (G*264, 4) x 256. bx -> (sl, r). r<8: gtok raw; else LN(x row of chunk c0+sl).
__global__ __launch_bounds__(256) void lng_k(const float* __restrict__ x, const float* __restrict__ gtok,
                                             const float* __restrict__ g, const float* __restrict__ be,
                                             bf16* __restrict__ lnxg, int c0) {
    int bx = blockIdx.x, b = blockIdx.y, tid = threadIdx.x;
    int sl = bx / 264, r = bx - sl * 264;
    bf16* orow = lnxg + (long)((sl * 4 + b) * 264 + r) * 1024 + tid * 4;
    if (r < MG) {
        float4 v = *(const float4*)(gtok + r * 1024 + tid * 4);
        orow[0] = __float2bfloat16(v.x); orow[1] = __float2bfloat16(v.y);
        orow[2] = __float2bfloat16(v.z); orow[3] = __float2bfloat16(v.w);
        return;
    }
    const float* row = x + (long)b * TD + ((long)(c0 + sl) * 256 + (r - MG)) * 1024;
    float4 v = *(const float4*)(row + tid * 4);
    float s = v.x + v.y + v.z + v.w;
    float q = v.x * v.x + v.y * v.y + v.z * v.z + v.w * v.w;
    for (int off = 32; off > 0; off >>= 1) { s += __shfl_down(s, off); q += __shfl_down(q, off); }
    __shared__ float red[10];
    int w = tid >> 6;
    if ((tid & 63) == 0) { red[w] = s; red[4 + w] = q; }
    __syncthreads();
    if (tid == 0) {
        float ts = red[0] + red[1] + red[2] + red[3];
        float tq = red[4] + red[5] + red[6] + red[7];
        float mean = ts * (1.f / Dm);
        float var = tq * (1.f / Dm) - mean * mean;
        red[8] = mean;
        red[9] = rsqrtf(var + 1e-5f);
    }
    __syncthreads();
    float mean = red[8], rstd = red[9];
    int d = tid * 4;
    float4 gv = *(const float4*)(g + d);
    float4 bv = *(const float4*)(be + d);
    orow[0] = __float2bfloat16((v.x - mean) * rstd * gv.x + bv.x);
    orow[1] = __float2bfloat16((v.y - mean) * rstd * gv.y + bv.y);
    orow[2] = __float2bfloat16((v.z - mean) * rstd * gv.z + bv.z);
    orow[3] = __float2bfloat16((v.w - mean) * rstd * gv.w + bv.w);
}

// ---------------- bf16 MFMA GEMM, 64xBN tile, BK=64 phases, 2-buffer ----------------
// Output paths: Cpart (split-K f32 partial) | Cf (f32 row-mapped + bias + optional residual Rz)
// | Cb (bf16 contiguous + bias + optional GELU).
template<int BN>
__global__ __launch_bounds__(256) void gemm64(
    const bf16* __restrict__ A, const bf16* __restrict__ W,
    int M, int N, int K, int kspan,
    bf16* __restrict__ Cb, int ldc, const float* __restrict__ bias, int gelu,
    float* __restrict__ Cpart, long partMN,
    float* __restrict__ Cf, const float* __restrict__ Rz, long roff2)
{
    constexpr int NSEG = 4 + BN / 16;     // 1KB segments per 32-k half
    constexpr int SEGW = NSEG / 4;        // segments per wave per half
    constexpr int FC   = BN / 64;
    constexpr int WN   = BN / 4;
    constexpr int HALFB = NSEG * 1024;    // bytes per 32-k half
    constexpr int PHB   = 2 * HALFB;      // bytes per 64-k phase buffer
    __shared__ short S[PHB];              // two phase buffers

    int tid = threadIdx.x;
    int w = tid >> 6, l = tid & 63;
    int m0 = blockIdx.y << 6, n0 = blockIdx.x * BN;
    long kb = (long)blockIdx.z * kspan;

    const bf16* gp[SEGW];
    int so[SEGW];
#pragma unroll
    for (int si = 0; si < SEGW; ++si) {
        int s = w + si * 4;
        const bf16* base = (s < 4) ? (A + (long)(m0 + s * 16 + (l >> 2)) * K)
                                   : (W + (long)(n0 + (s - 4) * 16 + (l >> 2)) * K);
        gp[si] = base + ((l & 3) << 3) + kb;
        so[si] = s * 1024 + l * 16;
    }
    char* cS = (char*)S;

    floatx4 acc[4][FC];
#pragma unroll
    for (int t = 0; t < 4; ++t)
#pragma unroll
        for (int u = 0; u < FC; ++u) acc[t][u] = (floatx4){0.f, 0.f, 0.f, 0.f};

    int arow = l & 15;
    int acol = (l >> 4) << 3;
    int np = kspan >> 6;

#define STAGE(p)                                                         \
    {                                                                    \
        int kt_ = (p) << 6;                                              \
        char* b_ = cS + ((p) & 1) * PHB;                                 \
        _Pragma("unroll")                                                \
        for (int si = 0; si < SEGW; ++si) {                              \
            gl16(gp[si] + kt_, b_ + so[si]);                             \
            gl16(gp[si] + kt_ + 32, b_ + HALFB + so[si]);                \
        }                                                                \
    }

    STAGE(0)
    for (int p = 0; p < np; ++p) {
        if (p + 1 < np) {
            STAGE(p + 1)
            if constexpr (SEGW == 2) asm volatile("s_waitcnt vmcnt(4)" ::: "memory");
            else                     asm volatile("s_waitcnt vmcnt(6)" ::: "memory");
        } else {
            asm volatile("s_waitcnt vmcnt(0)" ::: "memory");
        }
        __builtin_amdgcn_s_barrier();
        __builtin_amdgcn_sched_barrier(0);
        const short* buf = S + (p & 1) * (PHB / 2);
#pragma unroll
        for (int kh = 0; kh < 2; ++kh) {
            const short* hb = buf + kh * (HALFB / 2);
            short8 a[4], b[FC];
#pragma unroll
            for (int t = 0; t < 4; ++t)
                a[t] = *(const short8*)&hb[(t * 16 + arow) * 32 + acol];
#pragma unroll
            for (int u = 0; u < FC; ++u)
                b[u] = *(const short8*)&hb[2048 + (w * WN + u * 16 + arow) * 32 + acol];
#pragma unroll
            for (int t = 0; t < 4; ++t)
#pragma unroll
                for (int u = 0; u < FC; ++u)
                    acc[t][u] = __builtin_amdgcn_mfma_f32_16x16x32_bf16(a[t], b[u], acc[t][u], 0, 0, 0);
        }
        __builtin_amdgcn_sched_barrier(0);
        __builtin_amdgcn_s_barrier();
    }
#undef STAGE

    int crow0 = m0 + ((l >> 4) << 2);
    int ccol0 = n0 + w * WN + (l & 15);
    if (Cpart) {
        float* pp = Cpart + (long)blockIdx.z * partMN;
#pragma unroll
        for (int t = 0; t < 4; ++t)
#pragma unroll
            for (int rr = 0; rr < 4; ++rr) {
                int m = crow0 + t * 16 + rr;
                if (m >= M) continue;
#pragma unroll
                for (int u = 0; u < FC; ++u)
                    pp[(long)m * N + ccol0 + u * 16] = acc[t][u][rr];
            }
    } else if (Cf) {
        // f32 row-mapped (b = m>>8, r = m&255) + bias + optional residual
#pragma unroll
        for (int t = 0; t < 4; ++t)
#pragma unroll
            for (int rr = 0; rr < 4; ++rr) {
                int m = crow0 + t * 16 + rr;
                if (m >= M) continue;
                long ro = (long)(m >> 8) * TD + (roff2 + (m & 255)) * 1024L;
#pragma unroll
                for (int u = 0; u < FC; ++u) {
                    int n = ccol0 + u * 16;
                    float v = acc[t][u][rr] + bias[n];
                    if (Rz) v += Rz[ro + n];
                    Cf[ro + n] = v;
                }
            }
    } else {
#pragma unroll
        for (int t = 0; t < 4; ++t)
#pragma unroll
            for (int rr = 0; rr < 4; ++rr) {
                int m = crow0 + t * 16 + rr;
                if (m >= M) continue;
                bf16* crow = Cb + (long)m * ldc;
#pragma unroll
                for (int u = 0; u < FC; ++u) {
                    int n = ccol0 + u * 16;
                    float v = acc[t][u][rr];
                    if (bias) v += bias[n];
                    if (gelu) v = 0.5f * v * (1.f + erff(v * 0.70710678118654752f));
                    crow[n] = __float2bfloat16(v);
                }
            }
    }
}

// ---------------- FFN LayerNorm over c_pre (reads out, writes t_ln bf16) ----------------
__global__ __launch_bounds__(256) void reduce_ln_k(const float* __restrict__ cpre, long roff,
                                                   const float* __restrict__ g,
                                                   const float* __restrict__ be,
                                                   bf16* __restrict__ t_ln) {
    int m = blockIdx.x;                  // 0..1023
    int b = m >> 8, r = m & 255;
    int tid = threadIdx.x;
    long ro = (long)b * TD + (roff + r) * 1024L + tid * 4;
    float4 v = *(const float4*)(cpre + ro);
    float c0 = v.x, c1 = v.y, c2 = v.z, c3 = v.w;
    float sum = c0 + c1 + c2 + c3;
    float sq  = c0 * c0 + c1 * c1 + c2 * c2 + c3 * c3;
    for (int off = 32; off > 0; off >>= 1) { sum += __shfl_down(sum, off); sq += __shfl_down(sq, off); }
    __shared__ float red[10];
    int w = tid >> 6;
    if ((tid & 63) == 0) { red[w] = sum; red[4 + w] = sq; }
    __syncthreads();
    if (tid == 0) {
        float ts = red[0] + red[1] + red[2] + red[3];
        float tq = red[4] + red[5] + red[6] + red[7];
        float mean = ts * (1.f / Dm);
        float var = tq * (1.f / Dm) - mean * mean;
        red[8] = mean;
        red[9] = rsqrtf(var + 1e-5f);
    }
    __syncthreads();
    float mean = red[8], rstd = red[9];
    float4 gv = ((const float4*)g)[tid];
    float4 bev = ((const float4*)be)[tid];
    bf16* orow = t_ln + (long)(b * CHUNK + r) * Dm + tid * 4;
    orow[0] = __float2bfloat16((c0 - mean) * rstd * gv.x + bev.x);
    orow[1] = __float2bfloat16((c1 - mean) * rstd * gv.y + bev.y);
    orow[2] = __float2bfloat16((c2 - mean) * rstd * gv.z + bev.z);
    orow[3] = __float2bfloat16((c3 - mean) * rstd * gv.w + bev.w);
}

// ---------------- fused FFN2-reduce + residual + column partials ----------------
__global__ __launch_bounds__(256) void reduce_colpart_k(const float* __restrict__ part,
                                                        const float* __restrict__ bias,
                                                        float* __restrict__ out, long roff,
                                                        float* __restrict__ colp) {
    int b = blockIdx.x, rg = blockIdx.y, tid = threadIdx.x;
    float4 bv = ((const float4*)bias)[tid];
    float4 cs = make_float4(0.f, 0.f, 0.f, 0.f);
#pragma unroll
    for (int r8 = 0; r8 < 8; ++r8) {
        int r = rg * 8 + r8;
        int pi = (b * 256 + r) * 256 + tid;
        float4 s  = ((const float4*)part)[pi];
        float4 p2 = ((const float4*)(part + 1048576))[pi];
        long ro = (long)b * TD + (roff + r) * 1024L + tid * 4;
        float4 rv = *(const float4*)(out + ro);
        float4 v = make_float4(s.x + p2.x + bv.x + rv.x, s.y + p2.y + bv.y + rv.y,
                               s.z + p2.z + bv.z + rv.z, s.w + p2.w + bv.w + rv.w);
        *(float4*)(out + ro) = v;
        cs.x += v.x; cs.y += v.y; cs.z += v.z; cs.w += v.w;
    }
    *(float4*)(colp + ((b * 32 + rg) << 10) + tid * 4) = cs;
}

// ---------------- state update: grid (4, 32) x 256 thr; wave per ss output ----------------
__global__ __launch_bounds__(256) void state_update_k(const float* __restrict__ colp,
                                                      const float* __restrict__ Wsp,
                                                      const float* __restrict__ bsp,
                                                      float* __restrict__ st) {
    int b = blockIdx.x;
    int tid = threadIdx.x, w = tid >> 6, l = tid & 63;
    int ss = blockIdx.y * 4 + w;
    float4 m[4];
#pragma unroll
    for (int t = 0; t < 4; ++t) m[t] = make_float4(0.f, 0.f, 0.f, 0.f);
    for (int rg = 0; rg < 32; ++rg) {
        const float* pr = colp + ((b * 32 + rg) << 10) + l * 16;
#pragma unroll
        for (int t = 0; t < 4; ++t) {
            float4 v = *(const float4*)(pr + t * 4);
            m[t].x += v.x; m[t].y += v.y; m[t].z += v.z; m[t].w += v.w;
        }
    }
    const float* wr = Wsp + (long)ss * Dm + l * 16;
    float a = 0.f;
#pragma unroll
    for (int t = 0; t < 4; ++t) {
        float4 wv = *(const float4*)(wr + t * 4);
        a += m[t].x * wv.x + m[t].y * wv.y + m[t].z * wv.z + m[t].w * wv.w;
    }
    a *= (1.f / CHUNK);
    for (int off = 32; off > 0; off >>= 1) a += __shfl_down(a, off);
    if (l == 0) st[b * SDIM + ss] = a + bsp[ss];
}

// ---------------- attention: MFMA flash + in-block sib from st, 4 waves x 16 queries ----------------
__global__ __launch_bounds__(256) void attn_mfma_k(const bf16* __restrict__ qkv,
                                                   const float* __restrict__ st,
                                                   const bf16* __restrict__ Wf,
                                                   const float* __restrict__ bfused,
                                                   bf16* __restrict__ o_mat) {
    int qc = blockIdx.x, head = blockIdx.y, b = blockIdx.z;
    int kvh = head >> 2;
    int tid = threadIdx.x, w = tid >> 6, l = tid & 63;
    int m16 = l & 15, h4 = l >> 4;

    __shared__ short Qs[64][64];
    __shared__ short Ks[64][64];
    __shared__ short Vt[64][64];           // [dim][key]
    __shared__ short Ps[4][16][64];        // per-wave P tile [q][key]
    __shared__ float sq[64], sk[64], sv[64];

    const long rowq0 = (long)b * TC + MG + qc * 64;
    const bf16* kbase = qkv + ((long)b * TC) * 1536 + 1024 + kvh * DH;
    const bf16* vbase = kbase + 256;

    // in-block sib slices: 192 threads each compute one K=128 dot
    if (tid < 192) {
        int which = tid >> 6, nn = tid & 63;
        int n = (which == 0) ? head * 64 + nn
              : (which == 1) ? 1024 + kvh * 64 + nn
                             : 1280 + kvh * 64 + nn;
        const bf16* wr = Wf + (long)n * SDIM;
        const float* sr = st + b * SDIM;
        float a = bfused[n];
#pragma unroll
        for (int k8 = 0; k8 < 16; ++k8) {
            short8 wv = *(const short8*)(wr + k8 * 8);
#pragma unroll
            for (int e = 0; e < 8; ++e) a += sr[k8 * 8 + e] * b2f(wv[e]);
        }
        if (which == 0) sq[nn] = a; else if (which == 1) sk[nn] = a; else sv[nn] = a;
    }
    __syncthreads();

    // stage Q with sib add (all Q rows are chunk tokens)
#pragma unroll
    for (int p = 0; p < 2; ++p) {
        int rr = p * 32 + (tid >> 3);
        int c0 = (tid & 7) * 8;
        short8 v = *(const short8*)(qkv + (rowq0 + rr) * 1536 + head * DH + c0);
        short8 o;
#pragma unroll
        for (int e = 0; e < 8; ++e) o[e] = f2b(b2f(v[e]) + sq[c0 + e]);
        *(short8*)&Qs[rr][c0] = o;
    }

    float a_m[4] = {-1e30f, -1e30f, -1e30f, -1e30f};
    float a_l[4] = {0.f, 0.f, 0.f, 0.f};
    floatx4 acc_o[4];
#pragma unroll
    for (int dt = 0; dt < 4; ++dt) acc_o[dt] = (floatx4){0.f, 0.f, 0.f, 0.f};
    short8 aq[2];

    int qtok0 = MG + qc * 64 + w * 16 + h4 * 4;
    int ntiles = qc + 2;

    for (int t = 0; t < ntiles; ++t) {
        int jt = t * 64;
        // stage K with conditional sib add (rows >= MG only)
#pragma unroll
        for (int p = 0; p < 2; ++p) {
            int rr = p * 32 + (tid >> 3);
            int c0 = (tid & 7) * 8;
            int gk = min(jt + rr, TC - 1);
            short8 v = *(const short8*)(kbase + (long)gk * 1536 + c0);
            short8 o;
            if (gk >= MG) {
#pragma unroll
                for (int e = 0; e < 8; ++e) o[e] = f2b(b2f(v[e]) + sk[c0 + e]);
            } else o = v;
            *(short8*)&Ks[rr][c0] = o;
        }
        // stage V transposed with conditional sib add
#pragma unroll
        for (int p = 0; p < 2; ++p) {
            int cg = p * 4 + w;
            int gk = min(jt + l, TC - 1);
            short8 vv = *(const short8*)(vbase + (long)gk * 1536 + cg * 8);
            if (gk >= MG) {
#pragma unroll
                for (int e = 0; e < 8; ++e) vv[e] = f2b(b2f(vv[e]) + sv[cg * 8 + e]);
            }
#pragma unroll
            for (int e = 0; e < 8; ++e) Vt[cg * 8 + e][l] = vv[e];
        }
        __syncthreads();
        if (t == 0) {
            aq[0] = *(const short8*)&Qs[w * 16 + m16][h4 * 8];
            aq[1] = *(const short8*)&Qs[w * 16 + m16][32 + h4 * 8];
        }
        floatx4 s[4];
#pragma unroll
        for (int st_ = 0; st_ < 4; ++st_) {
            s[st_] = (floatx4){0.f, 0.f, 0.f, 0.f};
#pragma unroll
            for (int c = 0; c < 2; ++c) {
                short8 kf = *(const short8*)&Ks[st_ * 16 + m16][c * 32 + h4 * 8];
                s[st_] = __builtin_amdgcn_mfma_f32_16x16x32_bf16(aq[c], kf, s[st_], 0, 0, 0);
            }
        }
#pragma unroll
        for (int st_ = 0; st_ < 4; ++st_) {
            int keyg = jt + st_ * 16 + m16;
#pragma unroll
            for (int r = 0; r < 4; ++r) {
                float v = s[st_][r] * 0.125f;
                s[st_][r] = (keyg > qtok0 + r) ? -1e30f : v;
            }
        }
#pragma unroll
        for (int r = 0; r < 4; ++r) {
            float tm = fmaxf(fmaxf(s[0][r], s[1][r]), fmaxf(s[2][r], s[3][r]));
            tm = fmaxf(tm, __shfl_xor(tm, 1));
            tm = fmaxf(tm, __shfl_xor(tm, 2));
            tm = fmaxf(tm, __shfl_xor(tm, 4));
            tm = fmaxf(tm, __shfl_xor(tm, 8));
            float mn = fmaxf(a_m[r], tm);
            float rs = __expf(a_m[r] - mn);
            a_m[r] = mn;
            float ps = 0.f;
#pragma unroll
            for (int st_ = 0; st_ < 4; ++st_) {
                float p = __expf(s[st_][r] - mn);
                s[st_][r] = p;
                ps += p;
            }
            ps += __shfl_xor(ps, 1); ps += __shfl_xor(ps, 2);
            ps += __shfl_xor(ps, 4); ps += __shfl_xor(ps, 8);
            a_l[r] = a_l[r] * rs + ps;
#pragma unroll
            for (int dt = 0; dt < 4; ++dt) acc_o[dt][r] *= rs;
#pragma unroll
            for (int st_ = 0; st_ < 4; ++st_) {
                Ps[w][h4 * 4 + r][st_ * 16 + m16] = f2b(s[st_][r]);
            }
        }
#pragma unroll
        for (int c = 0; c < 2; ++c) {
            short8 ap = *(const short8*)&Ps[w][m16][c * 32 + h4 * 8];
#pragma unroll
            for (int dt = 0; dt < 4; ++dt) {
                short8 vf = *(const short8*)&Vt[dt * 16 + m16][c * 32 + h4 * 8];
                acc_o[dt] = __builtin_amdgcn_mfma_f32_16x16x32_bf16(ap, vf, acc_o[dt], 0, 0, 0);
            }
        }
        __syncthreads();
    }

#pragma unroll
    for (int r = 0; r < 4; ++r) {
        float inv = 1.f / a_l[r];
        long row = (long)b * CHUNK + qc * 64 + w * 16 + h4 * 4 + r;
#pragma unroll
        for (int dt = 0; dt < 4; ++dt)
            o_mat[row * Dm + head * DH + dt * 16 + m16] = __float2bfloat16(acc_o[dt][r] * inv);
    }
}

// ---------------- orchestration ----------------

extern "C" void kernel_launch(void* const* d_in, const int* in_sizes, int n_in,
                              void* d_out, int out_size, void* d_ws, size_t ws_size,
                              hipStream_t stream) {
    const float* x     = (const float*)d_in[0];
    const float* state = (const float*)d_in[1];
    const float* Wq    = (const float*)d_in[2];
    const float* Wk    = (const float*)d_in[3];
    const float* Wv    = (const float*)d_in[4];
    const float* Wo    = (const float*)d_in[5];
    const float* bo    = (const float*)d_in[6];
    const float* lag   = (const float*)d_in[7];
    const float* lab   = (const float*)d_in[8];
    const float* lfg   = (const float*)d_in[9];
    const float* lfb   = (const float*)d_in[10];
    const float* W1    = (const float*)d_in[11];
    const float* b1    = (const float*)d_in[12];
    const float* W2    = (const float*)d_in[13];
    const float* b2    = (const float*)d_in[14];
    const float* Wsp   = (const float*)d_in[15];
    const float* bsp   = (const float*)d_in[16];
    const float* Wsi   = (const float*)d_in[17];
    const float* bsi   = (const float*)d_in[18];
    const float* gtok  = (const float*)d_in[19];

    float* out = (float*)d_out;
    char*  wsb = (char*)d_ws;

    // QKV hoist group size: all 16 steps if workspace allows (~110MB), else 4
    const long stepQ = 4L * TC * 1536;                 // bf16 elems per step slot
    const int G = (ws_size >= (size_t)115000000) ? 16 : 4;

    // workspace layout (bytes)
    bf16* wqkv   = (bf16*)(wsb);                      // 1536x1024   3,145,728
    bf16* wo     = (bf16*)(wsb + 3145728);            // 1024x1024   2,097,152
    bf16* w1     = (bf16*)(wsb + 5242880);            // 4096x1024   8,388,608
    bf16* w2     = (bf16*)(wsb + 13631488);           // 1024x4096   8,388,608
    bf16* Wfused = (bf16*)(wsb + 22020096);           // 1536x128      393,216
    bf16* WsiT   = (bf16*)(wsb + 22413312);           // 128x1024      262,144
    float* bfused= (float*)(wsb + 22675456);          // 1536            6,144
    float* st    = (float*)(wsb + 22681600);          // 512             2,048
    bf16* qkvg   = (bf16*)(wsb + 22683648);           // G slots x 3,244,032 B
    char* R2     = wsb + 22683648 + (size_t)G * 3244032;
    // R2: lnxg (G*1056*1024*2 B, setup-transient) ∪ loop {u, part, scrB}
    bf16* lnxg   = (bf16*)R2;
    bf16* u      = (bf16*)R2;                          // 1024x4096 bf16 = 8,388,608
    float* part  = (float*)(R2 + 8388608);             // 2x1024x1024 f32 = 8,388,608
    char* scrB   = R2 + 16777216;                      // o_mat ∪ t_ln ∪ colp (2,097,152)
    bf16* o_mat  = (bf16*)scrB;
    bf16* t_ln   = (bf16*)scrB;
    float* colp  = (float*)scrB;                       // 4x32x1024 f32 = 512KB
    // G=16 total ≈ 109.2MB ; G=4 total ≈ 54.5MB

    // ---- setup ----
    vcopy_k<<<1, 512, 0, stream>>>(state, st, 512);
    cvt_bf16_k<<<1024, 256, 0, stream>>>(Wq, wqkv,            262144);
    cvt_bf16_k<<< 256, 256, 0, stream>>>(Wk, wqkv + 1048576,   65536);
    cvt_bf16_k<<< 256, 256, 0, stream>>>(Wv, wqkv + 1310720,   65536);
    cvt_bf16_k<<<1024, 256, 0, stream>>>(Wo, wo,              262144);
    cvt_bf16_k<<<4096, 256, 0, stream>>>(W1, w1,             1048576);
    cvt_bf16_k<<<4096, 256, 0, stream>>>(W2, w2,             1048576);
    wsiT_k<<<512, 256, 0, stream>>>(Wsi, WsiT);
    // Wfused = wqkv @ WsiT^T : M=1536, N=128, K=1024
    gemm64<64><<<dim3(2, 24, 1), 256, 0, stream>>>(
        wqkv, WsiT, 1536, 128, 1024, 1024,
        Wfused, 128, nullptr, 0, nullptr, 0L, nullptr, nullptr, 0L);
    bfused_k<<<24, 64, 0, stream>>>(wqkv, bsi, bfused);

    for (int s = 0; s < NSTEP; ++s) {
        long roff = (long)s * CHUNK;
        if (s % G == 0) {
            // LN(x)+gtok rows for G steps, then one QKV GEMM: M = G*1056
            lng_k<<<dim3(G * 264, 4), 256, 0, stream>>>(x, gtok, lag, lab, lnxg, s);
            gemm64<128><<<dim3(12, G * 1056 / 64, 1), 256, 0, stream>>>(
                lnxg, wqkv, G * 1056, 1536, 1024, 1024,
                qkvg, 1536, nullptr, 0, nullptr, 0L, nullptr, nullptr, 0L);
        }
        const bf16* qkv_s = qkvg + (long)(s % G) * stepQ;
        // attention with in-block sib correction (reads st directly)
        attn_mfma_k<<<dim3(4, 16, 4), 256, 0, stream>>>(qkv_s, st, Wfused, bfused, o_mat);
        // Wo (KS=1) with fused epilogue: out = acc + bo + x  (f32 c_pre)
        gemm64<64><<<dim3(16, 16, 1), 256, 0, stream>>>(
            o_mat, wo, Bn * CHUNK, 1024, 1024, 1024,
            nullptr, 0, bo, 0, nullptr, 0L, out, x, roff);
        // FFN LN (reads c_pre from out)
        reduce_ln_k<<<1024, 256, 0, stream>>>(out, roff, lfg, lfb, t_ln);
        // FFN1 + gelu -> u bf16
        gemm64<128><<<dim3(32, 16, 1), 256, 0, stream>>>(
            t_ln, w1, Bn * CHUNK, 4096, 1024, 1024,
            u, 4096, b1, 1, nullptr, 0L, nullptr, nullptr, 0L);
        // FFN2 split-K (KS=2) -> part; fused reduce(+b2,+c_pre) + column partials
        gemm64<64><<<dim3(16, 16, 2), 256, 0, stream>>>(
            u, w2, Bn * CHUNK, 1024, 4096, 2048,
            nullptr, 0, nullptr, 0, part, 1048576L, nullptr, nullptr, 0L);
        reduce_colpart_k<<<dim3(4, 32), 256, 0, stream>>>(part, b2, out, roff, colp);
        // state update (wide grid)
        state_update_k<<<dim3(4, 32), 256, 0, stream>>>(colp, Wsp, bsp, st);
    }
    vcopy_k<<<1, 512, 0, stream>>>(st, out + (long)Bn * Tn * Dm, 512);
}

// Round 15
// 1523.999 us; speedup vs baseline: 1.0837x; 1.0613x over previous
//
#include <hip/hip_runtime.h>
#include <hip/hip_bf16.h>

// Sizes
#define Dm    1024
#define Hn    16
#define KVH   4
#define DH    64
#define CHUNK 256
#define SDIM  128
#define MG    8
#define Bn    4
#define Tn    4096
#define TC    264            // MG + CHUNK
#define NSTEP 16
#define TD    4194304L       // Tn*Dm per batch

typedef __attribute__((ext_vector_type(8))) short short8;
typedef __attribute__((ext_vector_type(4))) float floatx4;
typedef __hip_bfloat16 bf16;

__device__ __forceinline__ void gl16(const void* g, void* l) {
    using GP = const __attribute__((address_space(1))) char*;
    using LP = __attribute__((address_space(3))) char*;
    __builtin_amdgcn_global_load_lds((GP)g, (LP)l, 16, 0, 0);
}
__device__ __forceinline__ float b2f(short s) {
    unsigned int u = ((unsigned int)(unsigned short)s) << 16;
    float f; __builtin_memcpy(&f, &u, 4); return f;
}
__device__ __forceinline__ short f2b(float f) {
    bf16 h = __float2bfloat16(f);
    short s; __builtin_memcpy(&s, &h, 2); return s;
}

// ---------------- utility kernels ----------------

__global__ __launch_bounds__(512) void vcopy_k(const float* __restrict__ s, float* __restrict__ d, int n) {
    int i = blockIdx.x * 512 + threadIdx.x;
    if (i < n) d[i] = s[i];
}

__global__ __launch_bounds__(256) void cvt_bf16_k(const float* __restrict__ s, bf16* __restrict__ d, int n4) {
    int i = blockIdx.x * 256 + threadIdx.x;
    if (i >= n4) return;
    float4 v = ((const float4*)s)[i];
    bf16* o = d + i * 4;
    o[0] = __float2bfloat16(v.x); o[1] = __float2bfloat16(v.y);
    o[2] = __float2bfloat16(v.z); o[3] = __float2bfloat16(v.w);
}

// WsiT[s][d] = bf16(Wsi[d][s])  (Wsi is [1024][128])
__global__ __launch_bounds__(256) void wsiT_k(const float* __restrict__ Wsi, bf16* __restrict__ WsiT) {
    int idx = blockIdx.x * 256 + threadIdx.x;     // 0..131071
    int s = idx >> 10, d = idx & 1023;
    WsiT[idx] = __float2bfloat16(Wsi[d * SDIM + s]);
}

// bfused[n] = wqkv[n] . bsi   (1536 outputs, K=1024)
__global__ __launch_bounds__(64) void bfused_k(const bf16* __restrict__ wqkv, const float* __restrict__ bsi,
                                               float* __restrict__ bfused) {
    int n = blockIdx.x * 64 + threadIdx.x;
    const bf16* wr = wqkv + (long)n * 1024;
    float a = 0.f;
    for (int k8 = 0; k8 < 128; ++k8) {
        short8 wv = *(const short8*)(wr + k8 * 8);
#pragma unroll
        for (int e = 0; e < 8; ++e) a += b2f(wv[e]) * bsi[k8 * 8 + e];
    }
    bfused[n] = a;
}

// group LN: grid (G*264, 4) x 256. bx -> (sl, r). r<8: gtok raw; else LN(x row of chunk c0+sl).
__global__ __launch_bounds__(256) void lng_k(const float* __restrict__ x, const float* __restrict__ gtok,
                                             const float* __restrict__ g, const float* __restrict__ be,
                                             bf16* __restrict__ lnxg, int c0) {
    int bx = blockIdx.x, b = blockIdx.y, tid = threadIdx.x;
    int sl = bx / 264, r = bx - sl * 264;
    bf16* orow = lnxg + (long)((sl * 4 + b) * 264 + r) * 1024 + tid * 4;
    if (r < MG) {
        float4 v = *(const float4*)(gtok + r * 1024 + tid * 4);
        orow[0] = __float2bfloat16(v.x); orow[1] = __float2bfloat16(v.y);
        orow[2] = __float2bfloat16(v.z); orow[3] = __float2bfloat16(v.w);
        return;
    }
    const float* row = x + (long)b * TD + ((long)(c0 + sl) * 256 + (r - MG)) * 1024;
    float4 v = *(const float4*)(row + tid * 4);
    float s = v.x + v.y + v.z + v.w;
    float q = v.x * v.x + v.y * v.y + v.z * v.z + v.w * v.w;
    for (int off = 32; off > 0; off >>= 1) { s += __shfl_down(s, off); q += __shfl_down(q, off); }
    __shared__ float red[10];
    int w = tid >> 6;
    if ((tid & 63) == 0) { red[w] = s; red[4 + w] = q; }
    __syncthreads();
    if (tid == 0) {
        float ts = red[0] + red[1] + red[2] + red[3];
        float tq = red[4] + red[5] + red[6] + red[7];
        float mean = ts * (1.f / Dm);
        float var = tq * (1.f / Dm) - mean * mean;
        red[8] = mean;
        red[9] = rsqrtf(var + 1e-5f);
    }
    __syncthreads();
    float mean = red[8], rstd = red[9];
    int d = tid * 4;
    float4 gv = *(const float4*)(g + d);
    float4 bv = *(const float4*)(be + d);
    orow[0] = __float2bfloat16((v.x - mean) * rstd * gv.x + bv.x);
    orow[1] = __float2bfloat16((v.y - mean) * rstd * gv.y + bv.y);
    orow[2] = __float2bfloat16((v.z - mean) * rstd * gv.z + bv.z);
    orow[3] = __float2bfloat16((v.w - mean) * rstd * gv.w + bv.w);
}

// ---------------- bf16 MFMA GEMM, 64xBN tile, BK=64 phases, 2-buffer, optional split-K ----------------
template<int BN>
__global__ __launch_bounds__(256) void gemm64(
    const bf16* __restrict__ A, const bf16* __restrict__ W,
    int M, int N, int K, int kspan,
    bf16* __restrict__ Cb, int ldc, const float* __restrict__ bias, int gelu,
    float* __restrict__ Cpart, long partMN)
{
    constexpr int NSEG = 4 + BN / 16;     // 1KB segments per 32-k half
    constexpr int SEGW = NSEG / 4;        // segments per wave per half
    constexpr int FC   = BN / 64;
    constexpr int WN   = BN / 4;
    constexpr int HALFB = NSEG * 1024;    // bytes per 32-k half
    constexpr int PHB   = 2 * HALFB;      // bytes per 64-k phase buffer
    __shared__ short S[PHB];              // two phase buffers

    int tid = threadIdx.x;
    int w = tid >> 6, l = tid & 63;
    int m0 = blockIdx.y << 6, n0 = blockIdx.x * BN;
    long kb = (long)blockIdx.z * kspan;

    const bf16* gp[SEGW];
    int so[SEGW];
#pragma unroll
    for (int si = 0; si < SEGW; ++si) {
        int s = w + si * 4;
        const bf16* base = (s < 4) ? (A + (long)(m0 + s * 16 + (l >> 2)) * K)
                                   : (W + (long)(n0 + (s - 4) * 16 + (l >> 2)) * K);
        gp[si] = base + ((l & 3) << 3) + kb;
        so[si] = s * 1024 + l * 16;
    }
    char* cS = (char*)S;

    floatx4 acc[4][FC];
#pragma unroll
    for (int t = 0; t < 4; ++t)
#pragma unroll
        for (int u = 0; u < FC; ++u) acc[t][u] = (floatx4){0.f, 0.f, 0.f, 0.f};

    int arow = l & 15;
    int acol = (l >> 4) << 3;
    int np = kspan >> 6;

#define STAGE(p)                                                         \
    {                                                                    \
        int kt_ = (p) << 6;                                              \
        char* b_ = cS + ((p) & 1) * PHB;                                 \
        _Pragma("unroll")                                                \
        for (int si = 0; si < SEGW; ++si) {                              \
            gl16(gp[si] + kt_, b_ + so[si]);                             \
            gl16(gp[si] + kt_ + 32, b_ + HALFB + so[si]);                \
        }                                                                \
    }

    STAGE(0)
    for (int p = 0; p < np; ++p) {
        if (p + 1 < np) {
            STAGE(p + 1)
            if constexpr (SEGW == 2) asm volatile("s_waitcnt vmcnt(4)" ::: "memory");
            else                     asm volatile("s_waitcnt vmcnt(6)" ::: "memory");
        } else {
            asm volatile("s_waitcnt vmcnt(0)" ::: "memory");
        }
        __builtin_amdgcn_s_barrier();
        __builtin_amdgcn_sched_barrier(0);
        const short* buf = S + (p & 1) * (PHB / 2);
#pragma unroll
        for (int kh = 0; kh < 2; ++kh) {
            const short* hb = buf + kh * (HALFB / 2);
            short8 a[4], b[FC];
#pragma unroll
            for (int t = 0; t < 4; ++t)
                a[t] = *(const short8*)&hb[(t * 16 + arow) * 32 + acol];
#pragma unroll
            for (int u = 0; u < FC; ++u)
                b[u] = *(const short8*)&hb[2048 + (w * WN + u * 16 + arow) * 32 + acol];
#pragma unroll
            for (int t = 0; t < 4; ++t)
#pragma unroll
                for (int u = 0; u < FC; ++u)
                    acc[t][u] = __builtin_amdgcn_mfma_f32_16x16x32_bf16(a[t], b[u], acc[t][u], 0, 0, 0);
        }
        __builtin_amdgcn_sched_barrier(0);
        __builtin_amdgcn_s_barrier();
    }
#undef STAGE

    int crow0 = m0 + ((l >> 4) << 2);
    int ccol0 = n0 + w * WN + (l & 15);
    if (Cpart) {
        float* pp = Cpart + (long)blockIdx.z * partMN;
#pragma unroll
        for (int t = 0; t < 4; ++t)
#pragma unroll
            for (int rr = 0; rr < 4; ++rr) {
                int m = crow0 + t * 16 + rr;
                if (m >= M) continue;
#pragma unroll
                for (int u = 0; u < FC; ++u)
                    pp[(long)m * N + ccol0 + u * 16] = acc[t][u][rr];
            }
    } else {
#pragma unroll
        for (int t = 0; t < 4; ++t)
#pragma unroll
            for (int rr = 0; rr < 4; ++rr) {
                int m = crow0 + t * 16 + rr;
                if (m >= M) continue;
                bf16* crow = Cb + (long)m * ldc;
#pragma unroll
                for (int u = 0; u < FC; ++u) {
                    int n = ccol0 + u * 16;
                    float v = acc[t][u][rr];
                    if (bias) v += bias[n];
                    if (gelu) v = 0.5f * v * (1.f + erff(v * 0.70710678118654752f));
                    crow[n] = __float2bfloat16(v);
                }
            }
    }
}

// ---------------- fused Wo-reduce + residual + FFN LayerNorm ----------------
__global__ __launch_bounds__(256) void reduce_ln_k(const float* __restrict__ part,
                                                   const float* __restrict__ bo,
                                                   const float* __restrict__ x,
                                                   float* __restrict__ out, long roff,
                                                   const float* __restrict__ g,
                                                   const float* __restrict__ be,
                                                   bf16* __restrict__ t_ln) {
    int m = blockIdx.x;                  // 0..1023
    int b = m >> 8, r = m & 255;
    int tid = threadIdx.x;
    long ro = (long)b * TD + (roff + r) * 1024L + tid * 4;
    int pi = m * 256 + tid;
    float4 s  = ((const float4*)part)[pi];
    float4 p2 = ((const float4*)(part + 1048576))[pi];
    float4 bv = ((const float4*)bo)[tid];
    float4 rv = *(const float4*)(x + ro);
    float c0 = s.x + p2.x + bv.x + rv.x;
    float c1 = s.y + p2.y + bv.y + rv.y;
    float c2 = s.z + p2.z + bv.z + rv.z;
    float c3 = s.w + p2.w + bv.w + rv.w;
    *(float4*)(out + ro) = make_float4(c0, c1, c2, c3);
    float sum = c0 + c1 + c2 + c3;
    float sq  = c0 * c0 + c1 * c1 + c2 * c2 + c3 * c3;
    for (int off = 32; off > 0; off >>= 1) { sum += __shfl_down(sum, off); sq += __shfl_down(sq, off); }
    __shared__ float red[10];
    int w = tid >> 6;
    if ((tid & 63) == 0) { red[w] = sum; red[4 + w] = sq; }
    __syncthreads();
    if (tid == 0) {
        float ts = red[0] + red[1] + red[2] + red[3];
        float tq = red[4] + red[5] + red[6] + red[7];
        float mean = ts * (1.f / Dm);
        float var = tq * (1.f / Dm) - mean * mean;
        red[8] = mean;
        red[9] = rsqrtf(var + 1e-5f);
    }
    __syncthreads();
    float mean = red[8], rstd = red[9];
    float4 gv = ((const float4*)g)[tid];
    float4 bev = ((const float4*)be)[tid];
    bf16* orow = t_ln + (long)(b * CHUNK + r) * Dm + tid * 4;
    orow[0] = __float2bfloat16((c0 - mean) * rstd * gv.x + bev.x);
    orow[1] = __float2bfloat16((c1 - mean) * rstd * gv.y + bev.y);
    orow[2] = __float2bfloat16((c2 - mean) * rstd * gv.z + bev.z);
    orow[3] = __float2bfloat16((c3 - mean) * rstd * gv.w + bev.w);
}

// ---------------- fused FFN2-reduce + residual + column partials ----------------
__global__ __launch_bounds__(256) void reduce_colpart_k(const float* __restrict__ part,
                                                        const float* __restrict__ bias,
                                                        float* __restrict__ out, long roff,
                                                        float* __restrict__ colp) {
    int b = blockIdx.x, rg = blockIdx.y, tid = threadIdx.x;
    float4 bv = ((const float4*)bias)[tid];
    float4 cs = make_float4(0.f, 0.f, 0.f, 0.f);
#pragma unroll
    for (int r8 = 0; r8 < 8; ++r8) {
        int r = rg * 8 + r8;
        int pi = (b * 256 + r) * 256 + tid;
        float4 s  = ((const float4*)part)[pi];
        float4 p2 = ((const float4*)(part + 1048576))[pi];
        long ro = (long)b * TD + (roff + r) * 1024L + tid * 4;
        float4 rv = *(const float4*)(out + ro);
        float4 v = make_float4(s.x + p2.x + bv.x + rv.x, s.y + p2.y + bv.y + rv.y,
                               s.z + p2.z + bv.z + rv.z, s.w + p2.w + bv.w + rv.w);
        *(float4*)(out + ro) = v;
        cs.x += v.x; cs.y += v.y; cs.z += v.z; cs.w += v.w;
    }
    *(float4*)(colp + ((b * 32 + rg) << 10) + tid * 4) = cs;
}

// ---------------- state update: grid (4, 32) x 256 thr; wave per ss output ----------------
__global__ __launch_bounds__(256) void state_update_k(const float* __restrict__ colp,
                                                      const float* __restrict__ Wsp,
                                                      const float* __restrict__ bsp,
                                                      float* __restrict__ st) {
    int b = blockIdx.x;
    int tid = threadIdx.x, w = tid >> 6, l = tid & 63;
    int ss = blockIdx.y * 4 + w;
    float4 m[4];
#pragma unroll
    for (int t = 0; t < 4; ++t) m[t] = make_float4(0.f, 0.f, 0.f, 0.f);
    for (int rg = 0; rg < 32; ++rg) {
        const float* pr = colp + ((b * 32 + rg) << 10) + l * 16;
#pragma unroll
        for (int t = 0; t < 4; ++t) {
            float4 v = *(const float4*)(pr + t * 4);
            m[t].x += v.x; m[t].y += v.y; m[t].z += v.z; m[t].w += v.w;
        }
    }
    const float* wr = Wsp + (long)ss * Dm + l * 16;
    float a = 0.f;
#pragma unroll
    for (int t = 0; t < 4; ++t) {
        float4 wv = *(const float4*)(wr + t * 4);
        a += m[t].x * wv.x + m[t].y * wv.y + m[t].z * wv.z + m[t].w * wv.w;
    }
    a *= (1.f / CHUNK);
    for (int off = 32; off > 0; off >>= 1) a += __shfl_down(a, off);
    if (l == 0) st[b * SDIM + ss] = a + bsp[ss];
}

// ---------------- attention: MFMA flash + in-block sib from st, 4 waves x 16 queries ----------------
__global__ __launch_bounds__(256) void attn_mfma_k(const bf16* __restrict__ qkv,
                                                   const float* __restrict__ st,
                                                   const bf16* __restrict__ Wf,
                                                   const float* __restrict__ bfused,
                                                   bf16* __restrict__ o_mat) {
    int qc = blockIdx.x, head = blockIdx.y, b = blockIdx.z;
    int kvh = head >> 2;
    int tid = threadIdx.x, w = tid >> 6, l = tid & 63;
    int m16 = l & 15, h4 = l >> 4;

    __shared__ short Qs[64][64];
    __shared__ short Ks[64][64];
    __shared__ short Vt[64][64];           // [dim][key]
    __shared__ short Ps[4][16][64];        // per-wave P tile [q][key]
    __shared__ float sq[64], sk[64], sv[64];

    const long rowq0 = (long)b * TC + MG + qc * 64;
    const bf16* kbase = qkv + ((long)b * TC) * 1536 + 1024 + kvh * DH;
    const bf16* vbase = kbase + 256;

    // in-block sib slices: 192 threads each compute one K=128 dot
    if (tid < 192) {
        int which = tid >> 6, nn = tid & 63;
        int n = (which == 0) ? head * 64 + nn
              : (which == 1) ? 1024 + kvh * 64 + nn
                             : 1280 + kvh * 64 + nn;
        const bf16* wr = Wf + (long)n * SDIM;
        const float* sr = st + b * SDIM;
        float a = bfused[n];
#pragma unroll
        for (int k8 = 0; k8 < 16; ++k8) {
            short8 wv = *(const short8*)(wr + k8 * 8);
#pragma unroll
            for (int e = 0; e < 8; ++e) a += sr[k8 * 8 + e] * b2f(wv[e]);
        }
        if (which == 0) sq[nn] = a; else if (which == 1) sk[nn] = a; else sv[nn] = a;
    }
    __syncthreads();

    // stage Q with sib add (all Q rows are chunk tokens)
#pragma unroll
    for (int p = 0; p < 2; ++p) {
        int rr = p * 32 + (tid >> 3);
        int c0 = (tid & 7) * 8;
        short8 v = *(const short8*)(qkv + (rowq0 + rr) * 1536 + head * DH + c0);
        short8 o;
#pragma unroll
        for (int e = 0; e < 8; ++e) o[e] = f2b(b2f(v[e]) + sq[c0 + e]);
        *(short8*)&Qs[rr][c0] = o;
    }

    float a_m[4] = {-1e30f, -1e30f, -1e30f, -1e30f};
    float a_l[4] = {0.f, 0.f, 0.f, 0.f};
    floatx4 acc_o[4];
#pragma unroll
    for (int dt = 0; dt < 4; ++dt) acc_o[dt] = (floatx4){0.f, 0.f, 0.f, 0.f};
    short8 aq[2];

    int qtok0 = MG + qc * 64 + w * 16 + h4 * 4;
    int ntiles = qc + 2;

    for (int t = 0; t < ntiles; ++t) {
        int jt = t * 64;
        // stage K with conditional sib add (rows >= MG only)
#pragma unroll
        for (int p = 0; p < 2; ++p) {
            int rr = p * 32 + (tid >> 3);
            int c0 = (tid & 7) * 8;
            int gk = min(jt + rr, TC - 1);
            short8 v = *(const short8*)(kbase + (long)gk * 1536 + c0);
            short8 o;
            if (gk >= MG) {
#pragma unroll
                for (int e = 0; e < 8; ++e) o[e] = f2b(b2f(v[e]) + sk[c0 + e]);
            } else o = v;
            *(short8*)&Ks[rr][c0] = o;
        }
        // stage V transposed with conditional sib add
#pragma unroll
        for (int p = 0; p < 2; ++p) {
            int cg = p * 4 + w;
            int gk = min(jt + l, TC - 1);
            short8 vv = *(const short8*)(vbase + (long)gk * 1536 + cg * 8);
            if (gk >= MG) {
#pragma unroll
                for (int e = 0; e < 8; ++e) vv[e] = f2b(b2f(vv[e]) + sv[cg * 8 + e]);
            }
#pragma unroll
            for (int e = 0; e < 8; ++e) Vt[cg * 8 + e][l] = vv[e];
        }
        __syncthreads();
        if (t == 0) {
            aq[0] = *(const short8*)&Qs[w * 16 + m16][h4 * 8];
            aq[1] = *(const short8*)&Qs[w * 16 + m16][32 + h4 * 8];
        }
        floatx4 s[4];
#pragma unroll
        for (int st_ = 0; st_ < 4; ++st_) {
            s[st_] = (floatx4){0.f, 0.f, 0.f, 0.f};
#pragma unroll
            for (int c = 0; c < 2; ++c) {
                short8 kf = *(const short8*)&Ks[st_ * 16 + m16][c * 32 + h4 * 8];
                s[st_] = __builtin_amdgcn_mfma_f32_16x16x32_bf16(aq[c], kf, s[st_], 0, 0, 0);
            }
        }
#pragma unroll
        for (int st_ = 0; st_ < 4; ++st_) {
            int keyg = jt + st_ * 16 + m16;
#pragma unroll
            for (int r = 0; r < 4; ++r) {
                float v = s[st_][r] * 0.125f;
                s[st_][r] = (keyg > qtok0 + r) ? -1e30f : v;
            }
        }
#pragma unroll
        for (int r = 0; r < 4; ++r) {
            float tm = fmaxf(fmaxf(s[0][r], s[1][r]), fmaxf(s[2][r], s[3][r]));
            tm = fmaxf(tm, __shfl_xor(tm, 1));
            tm = fmaxf(tm, __shfl_xor(tm, 2));
            tm = fmaxf(tm, __shfl_xor(tm, 4));
            tm = fmaxf(tm, __shfl_xor(tm, 8));
            float mn = fmaxf(a_m[r], tm);
            float rs = __expf(a_m[r] - mn);
            a_m[r] = mn;
            float ps = 0.f;
#pragma unroll
            for (int st_ = 0; st_ < 4; ++st_) {
                float p = __expf(s[st_][r] - mn);
                s[st_][r] = p;
                ps += p;
            }
            ps += __shfl_xor(ps, 1); ps += __shfl_xor(ps, 2);
            ps += __shfl_xor(ps, 4); ps += __shfl_xor(ps, 8);
            a_l[r] = a_l[r] * rs + ps;
#pragma unroll
            for (int dt = 0; dt < 4; ++dt) acc_o[dt][r] *= rs;
#pragma unroll
            for (int st_ = 0; st_ < 4; ++st_) {
                Ps[w][h4 * 4 + r][st_ * 16 + m16] = f2b(s[st_][r]);
            }
        }
#pragma unroll
        for (int c = 0; c < 2; ++c) {
            short8 ap = *(const short8*)&Ps[w][m16][c * 32 + h4 * 8];
#pragma unroll
            for (int dt = 0; dt < 4; ++dt) {
                short8 vf = *(const short8*)&Vt[dt * 16 + m16][c * 32 + h4 * 8];
                acc_o[dt] = __builtin_amdgcn_mfma_f32_16x16x32_bf16(ap, vf, acc_o[dt], 0, 0, 0);
            }
        }
        __syncthreads();
    }

#pragma unroll
    for (int r = 0; r < 4; ++r) {
        float inv = 1.f / a_l[r];
        long row = (long)b * CHUNK + qc * 64 + w * 16 + h4 * 4 + r;
#pragma unroll
        for (int dt = 0; dt < 4; ++dt)
            o_mat[row * Dm + head * DH + dt * 16 + m16] = __float2bfloat16(acc_o[dt][r] * inv);
    }
}

// ---------------- orchestration ----------------

extern "C" void kernel_launch(void* const* d_in, const int* in_sizes, int n_in,
                              void* d_out, int out_size, void* d_ws, size_t ws_size,
                              hipStream_t stream) {
    const float* x     = (const float*)d_in[0];
    const float* state = (const float*)d_in[1];
    const float* Wq    = (const float*)d_in[2];
    const float* Wk    = (const float*)d_in[3];
    const float* Wv    = (const float*)d_in[4];
    const float* Wo    = (const float*)d_in[5];
    const float* bo    = (const float*)d_in[6];
    const float* lag   = (const float*)d_in[7];
    const float* lab   = (const float*)d_in[8];
    const float* lfg   = (const float*)d_in[9];
    const float* lfb   = (const float*)d_in[10];
    const float* W1    = (const float*)d_in[11];
    const float* b1    = (const float*)d_in[12];
    const float* W2    = (const float*)d_in[13];
    const float* b2    = (const float*)d_in[14];
    const float* Wsp   = (const float*)d_in[15];
    const float* bsp   = (const float*)d_in[16];
    const float* Wsi   = (const float*)d_in[17];
    const float* bsi   = (const float*)d_in[18];
    const float* gtok  = (const float*)d_in[19];

    float* out = (float*)d_out;
    char*  wsb = (char*)d_ws;

    // QKV hoist group size: all 16 steps if workspace allows (~110MB), else 4
    const long stepQ = 4L * TC * 1536;                 // bf16 elems per step slot
    const int G = (ws_size >= (size_t)115000000) ? 16 : 4;

    // workspace layout (bytes)
    bf16* wqkv   = (bf16*)(wsb);                      // 1536x1024   3,145,728
    bf16* wo     = (bf16*)(wsb + 3145728);            // 1024x1024   2,097,152
    bf16* w1     = (bf16*)(wsb + 5242880);            // 4096x1024   8,388,608
    bf16* w2     = (bf16*)(wsb + 13631488);           // 1024x4096   8,388,608
    bf16* Wfused = (bf16*)(wsb + 22020096);           // 1536x128      393,216
    bf16* WsiT   = (bf16*)(wsb + 22413312);           // 128x1024      262,144
    float* bfused= (float*)(wsb + 22675456);          // 1536            6,144
    float* st    = (float*)(wsb + 22681600);          // 512             2,048
    bf16* qkvg   = (bf16*)(wsb + 22683648);           // G slots x 3,244,032 B
    char* R2     = wsb + 22683648 + (size_t)G * 3244032;
    // R2: lnxg (G*1056*1024*2 B, setup-transient) ∪ loop {u, part, scrB}
    bf16* lnxg   = (bf16*)R2;
    bf16* u      = (bf16*)R2;                          // 1024x4096 bf16 = 8,388,608
    float* part  = (float*)(R2 + 8388608);             // 2x1024x1024 f32 = 8,388,608
    char* scrB   = R2 + 16777216;                      // o_mat ∪ t_ln ∪ colp (2,097,152)
    bf16* o_mat  = (bf16*)scrB;
    bf16* t_ln   = (bf16*)scrB;
    float* colp  = (float*)scrB;                       // 4x32x1024 f32 = 512KB
    // G=16 total ≈ 109.2MB ; G=4 total ≈ 54.5MB

    // ---- setup ----
    vcopy_k<<<1, 512, 0, stream>>>(state, st, 512);
    cvt_bf16_k<<<1024, 256, 0, stream>>>(Wq, wqkv,            262144);
    cvt_bf16_k<<< 256, 256, 0, stream>>>(Wk, wqkv + 1048576,   65536);
    cvt_bf16_k<<< 256, 256, 0, stream>>>(Wv, wqkv + 1310720,   65536);
    cvt_bf16_k<<<1024, 256, 0, stream>>>(Wo, wo,              262144);
    cvt_bf16_k<<<4096, 256, 0, stream>>>(W1, w1,             1048576);
    cvt_bf16_k<<<4096, 256, 0, stream>>>(W2, w2,             1048576);
    wsiT_k<<<512, 256, 0, stream>>>(Wsi, WsiT);
    // Wfused = wqkv @ WsiT^T : M=1536, N=128, K=1024
    gemm64<64><<<dim3(2, 24, 1), 256, 0, stream>>>(
        wqkv, WsiT, 1536, 128, 1024, 1024,
        Wfused, 128, nullptr, 0, nullptr, 0L);
    bfused_k<<<24, 64, 0, stream>>>(wqkv, bsi, bfused);

    for (int s = 0; s < NSTEP; ++s) {
        long roff = (long)s * CHUNK;
        if (s % G == 0) {
            // LN(x)+gtok rows for G steps, then one QKV GEMM: M = G*1056
            lng_k<<<dim3(G * 264, 4), 256, 0, stream>>>(x, gtok, lag, lab, lnxg, s);
            gemm64<128><<<dim3(12, G * 1056 / 64, 1), 256, 0, stream>>>(
                lnxg, wqkv, G * 1056, 1536, 1024, 1024,
                qkvg, 1536, nullptr, 0, nullptr, 0L);
        }
        const bf16* qkv_s = qkvg + (long)(s % G) * stepQ;
        // attention with in-block sib correction (reads st directly)
        attn_mfma_k<<<dim3(4, 16, 4), 256, 0, stream>>>(qkv_s, st, Wfused, bfused, o_mat);
        // Wo split-K (KS=2), BN=64 -> part; fused reduce(+bo,+x) + FFN LN
        gemm64<64><<<dim3(16, 16, 2), 256, 0, stream>>>(
            o_mat, wo, Bn * CHUNK, 1024, 1024, 512,
            nullptr, 0, nullptr, 0, part, 1048576L);
        reduce_ln_k<<<1024, 256, 0, stream>>>(part, bo, x, out, roff, lfg, lfb, t_ln);
        // FFN1 + gelu -> u bf16
        gemm64<128><<<dim3(32, 16, 1), 256, 0, stream>>>(
            t_ln, w1, Bn * CHUNK, 4096, 1024, 1024,
            u, 4096, b1, 1, nullptr, 0L);
        // FFN2 split-K (KS=2), BN=64 -> part; fused reduce(+b2,+c_pre) + column partials
        gemm64<64><<<dim3(16, 16, 2), 256, 0, stream>>>(
            u, w2, Bn * CHUNK, 1024, 4096, 2048,
            nullptr, 0, nullptr, 0, part, 1048576L);
        reduce_colpart_k<<<dim3(4, 32), 256, 0, stream>>>(part, b2, out, roff, colp);
        // state update (wide grid)
        state_update_k<<<dim3(4, 32), 256, 0, stream>>>(colp, Wsp, bsp, st);
    }
    vcopy_k<<<1, 512, 0, stream>>>(st, out + (long)Bn * Tn * Dm, 512);
}

// Round 16
// 1508.664 us; speedup vs baseline: 1.0947x; 1.0102x over previous
//
#include <hip/hip_runtime.h>
#include <hip/hip_bf16.h>

// Sizes
#define Dm    1024
#define Hn    16
#define KVH   4
#define DH    64
#define CHUNK 256
#define SDIM  128
#define MG    8
#define Bn    4
#define Tn    4096
#define TC    264            // MG + CHUNK
#define NSTEP 16
#define TD    4194304L       // Tn*Dm per batch

typedef __attribute__((ext_vector_type(8))) short short8;
typedef __attribute__((ext_vector_type(4))) float floatx4;
typedef __hip_bfloat16 bf16;

__device__ __forceinline__ void gl16(const void* g, void* l) {
    using GP = const __attribute__((address_space(1))) char*;
    using LP = __attribute__((address_space(3))) char*;
    __builtin_amdgcn_global_load_lds((GP)g, (LP)l, 16, 0, 0);
}
__device__ __forceinline__ float b2f(short s) {
    unsigned int u = ((unsigned int)(unsigned short)s) << 16;
    float f; __builtin_memcpy(&f, &u, 4); return f;
}
__device__ __forceinline__ short f2b(float f) {
    bf16 h = __float2bfloat16(f);
    short s; __builtin_memcpy(&s, &h, 2); return s;
}

// ---------------- utility kernels ----------------

__global__ __launch_bounds__(512) void vcopy_k(const float* __restrict__ s, float* __restrict__ d, int n) {
    int i = blockIdx.x * 512 + threadIdx.x;
    if (i < n) d[i] = s[i];
}

__global__ __launch_bounds__(256) void cvt_bf16_k(const float* __restrict__ s, bf16* __restrict__ d, int n4) {
    int i = blockIdx.x * 256 + threadIdx.x;
    if (i >= n4) return;
    float4 v = ((const float4*)s)[i];
    bf16* o = d + i * 4;
    o[0] = __float2bfloat16(v.x); o[1] = __float2bfloat16(v.y);
    o[2] = __float2bfloat16(v.z); o[3] = __float2bfloat16(v.w);
}

// WsiT[s][d] = bf16(Wsi[d][s])  (Wsi is [1024][128])
__global__ __launch_bounds__(256) void wsiT_k(const float* __restrict__ Wsi, bf16* __restrict__ WsiT) {
    int idx = blockIdx.x * 256 + threadIdx.x;     // 0..131071
    int s = idx >> 10, d = idx & 1023;
    WsiT[idx] = __float2bfloat16(Wsi[d * SDIM + s]);
}

// bfused[n] = wqkv[n] . bsi   (1536 outputs, K=1024)
__global__ __launch_bounds__(64) void bfused_k(const bf16* __restrict__ wqkv, const float* __restrict__ bsi,
                                               float* __restrict__ bfused) {
    int n = blockIdx.x * 64 + threadIdx.x;
    const bf16* wr = wqkv + (long)n * 1024;
    float a = 0.f;
    for (int k8 = 0; k8 < 128; ++k8) {
        short8 wv = *(const short8*)(wr + k8 * 8);
#pragma unroll
        for (int e = 0; e < 8; ++e) a += b2f(wv[e]) * bsi[k8 * 8 + e];
    }
    bfused[n] = a;
}

// group LN: grid (G*264, 4) x 256. bx -> (sl, r). r<8: gtok raw; else LN(x row of chunk c0+sl).
__global__ __launch_bounds__(256) void lng_k(const float* __restrict__ x, const float* __restrict__ gtok,
                                             const float* __restrict__ g, const float* __restrict__ be,
                                             bf16* __restrict__ lnxg, int c0) {
    int bx = blockIdx.x, b = blockIdx.y, tid = threadIdx.x;
    int sl = bx / 264, r = bx - sl * 264;
    bf16* orow = lnxg + (long)((sl * 4 + b) * 264 + r) * 1024 + tid * 4;
    if (r < MG) {
        float4 v = *(const float4*)(gtok + r * 1024 + tid * 4);
        orow[0] = __float2bfloat16(v.x); orow[1] = __float2bfloat16(v.y);
        orow[2] = __float2bfloat16(v.z); orow[3] = __float2bfloat16(v.w);
        return;
    }
    const float* row = x + (long)b * TD + ((long)(c0 + sl) * 256 + (r - MG)) * 1024;
    float4 v = *(const float4*)(row + tid * 4);
    float s = v.x + v.y + v.z + v.w;
    float q = v.x * v.x + v.y * v.y + v.z * v.z + v.w * v.w;
    for (int off = 32; off > 0; off >>= 1) { s += __shfl_down(s, off); q += __shfl_down(q, off); }
    __shared__ float red[10];
    int w = tid >> 6;
    if ((tid & 63) == 0) { red[w] = s; red[4 + w] = q; }
    __syncthreads();
    if (tid == 0) {
        float ts = red[0] + red[1] + red[2] + red[3];
        float tq = red[4] + red[5] + red[6] + red[7];
        float mean = ts * (1.f / Dm);
        float var = tq * (1.f / Dm) - mean * mean;
        red[8] = mean;
        red[9] = rsqrtf(var + 1e-5f);
    }
    __syncthreads();
    float mean = red[8], rstd = red[9];
    int d = tid * 4;
    float4 gv = *(const float4*)(g + d);
    float4 bv = *(const float4*)(be + d);
    orow[0] = __float2bfloat16((v.x - mean) * rstd * gv.x + bv.x);
    orow[1] = __float2bfloat16((v.y - mean) * rstd * gv.y + bv.y);
    orow[2] = __float2bfloat16((v.z - mean) * rstd * gv.z + bv.z);
    orow[3] = __float2bfloat16((v.w - mean) * rstd * gv.w + bv.w);
}

// ---------------- bf16 MFMA GEMM, 64xBN tile, BK=64 phases, 2-buffer, optional split-K ----------------
// LDS bank-swizzle (T2, rule #21): dest linear for global_load_lds; global SOURCE pre-permuted
// (lane lp = l ^ ((l>>3)&3)); reads XOR col bits 3-4 (shorts) with row bits 1-2.
template<int BN>
__global__ __launch_bounds__(256) void gemm64(
    const bf16* __restrict__ A, const bf16* __restrict__ W,
    int M, int N, int K, int kspan,
    bf16* __restrict__ Cb, int ldc, const float* __restrict__ bias, int gelu,
    float* __restrict__ Cpart, long partMN)
{
    constexpr int NSEG = 4 + BN / 16;     // 1KB segments per 32-k half
    constexpr int SEGW = NSEG / 4;        // segments per wave per half
    constexpr int FC   = BN / 64;
    constexpr int WN   = BN / 4;
    constexpr int HALFB = NSEG * 1024;    // bytes per 32-k half
    constexpr int PHB   = 2 * HALFB;      // bytes per 64-k phase buffer
    __shared__ short S[PHB];              // two phase buffers

    int tid = threadIdx.x;
    int w = tid >> 6, l = tid & 63;
    int m0 = blockIdx.y << 6, n0 = blockIdx.x * BN;
    long kb = (long)blockIdx.z * kspan;

    int lp = l ^ ((l >> 3) & 3);          // swizzled source lane (involution)
    const bf16* gp[SEGW];
    int so[SEGW];
#pragma unroll
    for (int si = 0; si < SEGW; ++si) {
        int s = w + si * 4;
        const bf16* base = (s < 4) ? (A + (long)(m0 + s * 16 + (lp >> 2)) * K)
                                   : (W + (long)(n0 + (s - 4) * 16 + (lp >> 2)) * K);
        gp[si] = base + ((lp & 3) << 3) + kb;
        so[si] = s * 1024 + l * 16;       // LDS dest stays linear (base + lane*16)
    }
    char* cS = (char*)S;

    floatx4 acc[4][FC];
#pragma unroll
    for (int t = 0; t < 4; ++t)
#pragma unroll
        for (int u = 0; u < FC; ++u) acc[t][u] = (floatx4){0.f, 0.f, 0.f, 0.f};

    int arow = l & 15;
    int acol = ((l >> 4) << 3) ^ (((arow >> 1) & 3) << 3);   // swizzled read col (shorts)
    int np = kspan >> 6;

#define STAGE(p)                                                         \
    {                                                                    \
        int kt_ = (p) << 6;                                              \
        char* b_ = cS + ((p) & 1) * PHB;                                 \
        _Pragma("unroll")                                                \
        for (int si = 0; si < SEGW; ++si) {                              \
            gl16(gp[si] + kt_, b_ + so[si]);                             \
            gl16(gp[si] + kt_ + 32, b_ + HALFB + so[si]);                \
        }                                                                \
    }

    STAGE(0)
    for (int p = 0; p < np; ++p) {
        if (p + 1 < np) {
            STAGE(p + 1)
            if constexpr (SEGW == 2) asm volatile("s_waitcnt vmcnt(4)" ::: "memory");
            else                     asm volatile("s_waitcnt vmcnt(6)" ::: "memory");
        } else {
            asm volatile("s_waitcnt vmcnt(0)" ::: "memory");
        }
        __builtin_amdgcn_s_barrier();
        __builtin_amdgcn_sched_barrier(0);
        const short* buf = S + (p & 1) * (PHB / 2);
#pragma unroll
        for (int kh = 0; kh < 2; ++kh) {
            const short* hb = buf + kh * (HALFB / 2);
            short8 a[4], b[FC];
#pragma unroll
            for (int t = 0; t < 4; ++t)
                a[t] = *(const short8*)&hb[(t * 16 + arow) * 32 + acol];
#pragma unroll
            for (int u = 0; u < FC; ++u)
                b[u] = *(const short8*)&hb[2048 + (w * WN + u * 16 + arow) * 32 + acol];
#pragma unroll
            for (int t = 0; t < 4; ++t)
#pragma unroll
                for (int u = 0; u < FC; ++u)
                    acc[t][u] = __builtin_amdgcn_mfma_f32_16x16x32_bf16(a[t], b[u], acc[t][u], 0, 0, 0);
        }
        __builtin_amdgcn_sched_barrier(0);
        __builtin_amdgcn_s_barrier();
    }
#undef STAGE

    int crow0 = m0 + ((l >> 4) << 2);
    int ccol0 = n0 + w * WN + (l & 15);
    if (Cpart) {
        float* pp = Cpart + (long)blockIdx.z * partMN;
#pragma unroll
        for (int t = 0; t < 4; ++t)
#pragma unroll
            for (int rr = 0; rr < 4; ++rr) {
                int m = crow0 + t * 16 + rr;
                if (m >= M) continue;
#pragma unroll
                for (int u = 0; u < FC; ++u)
                    pp[(long)m * N + ccol0 + u * 16] = acc[t][u][rr];
            }
    } else {
#pragma unroll
        for (int t = 0; t < 4; ++t)
#pragma unroll
            for (int rr = 0; rr < 4; ++rr) {
                int m = crow0 + t * 16 + rr;
                if (m >= M) continue;
                bf16* crow = Cb + (long)m * ldc;
#pragma unroll
                for (int u = 0; u < FC; ++u) {
                    int n = ccol0 + u * 16;
                    float v = acc[t][u][rr];
                    if (bias) v += bias[n];
                    if (gelu) v = 0.5f * v * (1.f + erff(v * 0.70710678118654752f));
                    crow[n] = __float2bfloat16(v);
                }
            }
    }
}

// ---------------- fused Wo-reduce + residual + FFN LayerNorm ----------------
__global__ __launch_bounds__(256) void reduce_ln_k(const float* __restrict__ part,
                                                   const float* __restrict__ bo,
                                                   const float* __restrict__ x,
                                                   float* __restrict__ out, long roff,
                                                   const float* __restrict__ g,
                                                   const float* __restrict__ be,
                                                   bf16* __restrict__ t_ln) {
    int m = blockIdx.x;                  // 0..1023
    int b = m >> 8, r = m & 255;
    int tid = threadIdx.x;
    long ro = (long)b * TD + (roff + r) * 1024L + tid * 4;
    int pi = m * 256 + tid;
    float4 s  = ((const float4*)part)[pi];
    float4 p2 = ((const float4*)(part + 1048576))[pi];
    float4 bv = ((const float4*)bo)[tid];
    float4 rv = *(const float4*)(x + ro);
    float c0 = s.x + p2.x + bv.x + rv.x;
    float c1 = s.y + p2.y + bv.y + rv.y;
    float c2 = s.z + p2.z + bv.z + rv.z;
    float c3 = s.w + p2.w + bv.w + rv.w;
    *(float4*)(out + ro) = make_float4(c0, c1, c2, c3);
    float sum = c0 + c1 + c2 + c3;
    float sq  = c0 * c0 + c1 * c1 + c2 * c2 + c3 * c3;
    for (int off = 32; off > 0; off >>= 1) { sum += __shfl_down(sum, off); sq += __shfl_down(sq, off); }
    __shared__ float red[10];
    int w = tid >> 6;
    if ((tid & 63) == 0) { red[w] = sum; red[4 + w] = sq; }
    __syncthreads();
    if (tid == 0) {
        float ts = red[0] + red[1] + red[2] + red[3];
        float tq = red[4] + red[5] + red[6] + red[7];
        float mean = ts * (1.f / Dm);
        float var = tq * (1.f / Dm) - mean * mean;
        red[8] = mean;
        red[9] = rsqrtf(var + 1e-5f);
    }
    __syncthreads();
    float mean = red[8], rstd = red[9];
    float4 gv = ((const float4*)g)[tid];
    float4 bev = ((const float4*)be)[tid];
    bf16* orow = t_ln + (long)(b * CHUNK + r) * Dm + tid * 4;
    orow[0] = __float2bfloat16((c0 - mean) * rstd * gv.x + bev.x);
    orow[1] = __float2bfloat16((c1 - mean) * rstd * gv.y + bev.y);
    orow[2] = __float2bfloat16((c2 - mean) * rstd * gv.z + bev.z);
    orow[3] = __float2bfloat16((c3 - mean) * rstd * gv.w + bev.w);
}

// ---------------- fused FFN2-reduce + residual + column partials ----------------
__global__ __launch_bounds__(256) void reduce_colpart_k(const float* __restrict__ part,
                                                        const float* __restrict__ bias,
                                                        float* __restrict__ out, long roff,
                                                        float* __restrict__ colp) {
    int b = blockIdx.x, rg = blockIdx.y, tid = threadIdx.x;
    float4 bv = ((const float4*)bias)[tid];
    float4 cs = make_float4(0.f, 0.f, 0.f, 0.f);
#pragma unroll
    for (int r8 = 0; r8 < 8; ++r8) {
        int r = rg * 8 + r8;
        int pi = (b * 256 + r) * 256 + tid;
        float4 s  = ((const float4*)part)[pi];
        float4 p2 = ((const float4*)(part + 1048576))[pi];
        long ro = (long)b * TD + (roff + r) * 1024L + tid * 4;
        float4 rv = *(const float4*)(out + ro);
        float4 v = make_float4(s.x + p2.x + bv.x + rv.x, s.y + p2.y + bv.y + rv.y,
                               s.z + p2.z + bv.z + rv.z, s.w + p2.w + bv.w + rv.w);
        *(float4*)(out + ro) = v;
        cs.x += v.x; cs.y += v.y; cs.z += v.z; cs.w += v.w;
    }
    *(float4*)(colp + ((b * 32 + rg) << 10) + tid * 4) = cs;
}

// ---------------- state update: grid (4, 32) x 256 thr; wave per ss output ----------------
__global__ __launch_bounds__(256) void state_update_k(const float* __restrict__ colp,
                                                      const float* __restrict__ Wsp,
                                                      const float* __restrict__ bsp,
                                                      float* __restrict__ st) {
    int b = blockIdx.x;
    int tid = threadIdx.x, w = tid >> 6, l = tid & 63;
    int ss = blockIdx.y * 4 + w;
    float4 m[4];
#pragma unroll
    for (int t = 0; t < 4; ++t) m[t] = make_float4(0.f, 0.f, 0.f, 0.f);
    for (int rg = 0; rg < 32; ++rg) {
        const float* pr = colp + ((b * 32 + rg) << 10) + l * 16;
#pragma unroll
        for (int t = 0; t < 4; ++t) {
            float4 v = *(const float4*)(pr + t * 4);
            m[t].x += v.x; m[t].y += v.y; m[t].z += v.z; m[t].w += v.w;
        }
    }
    const float* wr = Wsp + (long)ss * Dm + l * 16;
    float a = 0.f;
#pragma unroll
    for (int t = 0; t < 4; ++t) {
        float4 wv = *(const float4*)(wr + t * 4);
        a += m[t].x * wv.x + m[t].y * wv.y + m[t].z * wv.z + m[t].w * wv.w;
    }
    a *= (1.f / CHUNK);
    for (int off = 32; off > 0; off >>= 1) a += __shfl_down(a, off);
    if (l == 0) st[b * SDIM + ss] = a + bsp[ss];
}

// ---------------- attention: MFMA flash + in-block sib from st, 4 waves x 16 queries ----------------
__global__ __launch_bounds__(256) void attn_mfma_k(const bf16* __restrict__ qkv,
                                                   const float* __restrict__ st,
                                                   const bf16* __restrict__ Wf,
                                                   const float* __restrict__ bfused,
                                                   bf16* __restrict__ o_mat) {
    int qc = blockIdx.x, head = blockIdx.y, b = blockIdx.z;
    int kvh = head >> 2;
    int tid = threadIdx.x, w = tid >> 6, l = tid & 63;
    int m16 = l & 15, h4 = l >> 4;

    __shared__ short Qs[64][64];
    __shared__ short Ks[64][64];
    __shared__ short Vt[64][64];           // [dim][key]
    __shared__ short Ps[4][16][64];        // per-wave P tile [q][key]
    __shared__ float sq[64], sk[64], sv[64];

    const long rowq0 = (long)b * TC + MG + qc * 64;
    const bf16* kbase = qkv + ((long)b * TC) * 1536 + 1024 + kvh * DH;
    const bf16* vbase = kbase + 256;

    // in-block sib slices: 192 threads each compute one K=128 dot
    if (tid < 192) {
        int which = tid >> 6, nn = tid & 63;
        int n = (which == 0) ? head * 64 + nn
              : (which == 1) ? 1024 + kvh * 64 + nn
                             : 1280 + kvh * 64 + nn;
        const bf16* wr = Wf + (long)n * SDIM;
        const float* sr = st + b * SDIM;
        float a = bfused[n];
#pragma unroll
        for (int k8 = 0; k8 < 16; ++k8) {
            short8 wv = *(const short8*)(wr + k8 * 8);
#pragma unroll
            for (int e = 0; e < 8; ++e) a += sr[k8 * 8 + e] * b2f(wv[e]);
        }
        if (which == 0) sq[nn] = a; else if (which == 1) sk[nn] = a; else sv[nn] = a;
    }
    __syncthreads();

    // stage Q with sib add (all Q rows are chunk tokens)
#pragma unroll
    for (int p = 0; p < 2; ++p) {
        int rr = p * 32 + (tid >> 3);
        int c0 = (tid & 7) * 8;
        short8 v = *(const short8*)(qkv + (rowq0 + rr) * 1536 + head * DH + c0);
        short8 o;
#pragma unroll
        for (int e = 0; e < 8; ++e) o[e] = f2b(b2f(v[e]) + sq[c0 + e]);
        *(short8*)&Qs[rr][c0] = o;
    }

    float a_m[4] = {-1e30f, -1e30f, -1e30f, -1e30f};
    float a_l[4] = {0.f, 0.f, 0.f, 0.f};
    floatx4 acc_o[4];
#pragma unroll
    for (int dt = 0; dt < 4; ++dt) acc_o[dt] = (floatx4){0.f, 0.f, 0.f, 0.f};
    short8 aq[2];

    int qtok0 = MG + qc * 64 + w * 16 + h4 * 4;
    int ntiles = qc + 2;

    for (int t = 0; t < ntiles; ++t) {
        int jt = t * 64;
        // stage K with conditional sib add (rows >= MG only)
#pragma unroll
        for (int p = 0; p < 2; ++p) {
            int rr = p * 32 + (tid >> 3);
            int c0 = (tid & 7) * 8;
            int gk = min(jt + rr, TC - 1);
            short8 v = *(const short8*)(kbase + (long)gk * 1536 + c0);
            short8 o;
            if (gk >= MG) {
#pragma unroll
                for (int e = 0; e < 8; ++e) o[e] = f2b(b2f(v[e]) + sk[c0 + e]);
            } else o = v;
            *(short8*)&Ks[rr][c0] = o;
        }
        // stage V transposed with conditional sib add
#pragma unroll
        for (int p = 0; p < 2; ++p) {
            int cg = p * 4 + w;
            int gk = min(jt + l, TC - 1);
            short8 vv = *(const short8*)(vbase + (long)gk * 1536 + cg * 8);
            if (gk >= MG) {
#pragma unroll
                for (int e = 0; e < 8; ++e) vv[e] = f2b(b2f(vv[e]) + sv[cg * 8 + e]);
            }
#pragma unroll
            for (int e = 0; e < 8; ++e) Vt[cg * 8 + e][l] = vv[e];
        }
        __syncthreads();
        if (t == 0) {
            aq[0] = *(const short8*)&Qs[w * 16 + m16][h4 * 8];
            aq[1] = *(const short8*)&Qs[w * 16 + m16][32 + h4 * 8];
        }
        floatx4 s[4];
#pragma unroll
        for (int st_ = 0; st_ < 4; ++st_) {
            s[st_] = (floatx4){0.f, 0.f, 0.f, 0.f};
#pragma unroll
            for (int c = 0; c < 2; ++c) {
                short8 kf = *(const short8*)&Ks[st_ * 16 + m16][c * 32 + h4 * 8];
                s[st_] = __builtin_amdgcn_mfma_f32_16x16x32_bf16(aq[c], kf, s[st_], 0, 0, 0);
            }
        }
#pragma unroll
        for (int st_ = 0; st_ < 4; ++st_) {
            int keyg = jt + st_ * 16 + m16;
#pragma unroll
            for (int r = 0; r < 4; ++r) {
                float v = s[st_][r] * 0.125f;
                s[st_][r] = (keyg > qtok0 + r) ? -1e30f : v;
            }
        }
#pragma unroll
        for (int r = 0; r < 4; ++r) {
            float tm = fmaxf(fmaxf(s[0][r], s[1][r]), fmaxf(s[2][r], s[3][r]));
            tm = fmaxf(tm, __shfl_xor(tm, 1));
            tm = fmaxf(tm, __shfl_xor(tm, 2));
            tm = fmaxf(tm, __shfl_xor(tm, 4));
            tm = fmaxf(tm, __shfl_xor(tm, 8));
            float mn = fmaxf(a_m[r], tm);
            float rs = __expf(a_m[r] - mn);
            a_m[r] = mn;
            float ps = 0.f;
#pragma unroll
            for (int st_ = 0; st_ < 4; ++st_) {
                float p = __expf(s[st_][r] - mn);
                s[st_][r] = p;
                ps += p;
            }
            ps += __shfl_xor(ps, 1); ps += __shfl_xor(ps, 2);
            ps += __shfl_xor(ps, 4); ps += __shfl_xor(ps, 8);
            a_l[r] = a_l[r] * rs + ps;
#pragma unroll
            for (int dt = 0; dt < 4; ++dt) acc_o[dt][r] *= rs;
#pragma unroll
            for (int st_ = 0; st_ < 4; ++st_) {
                Ps[w][h4 * 4 + r][st_ * 16 + m16] = f2b(s[st_][r]);
            }
        }
#pragma unroll
        for (int c = 0; c < 2; ++c) {
            short8 ap = *(const short8*)&Ps[w][m16][c * 32 + h4 * 8];
#pragma unroll
            for (int dt = 0; dt < 4; ++dt) {
                short8 vf = *(const short8*)&Vt[dt * 16 + m16][c * 32 + h4 * 8];
                acc_o[dt] = __builtin_amdgcn_mfma_f32_16x16x32_bf16(ap, vf, acc_o[dt], 0, 0, 0);
            }
        }
        __syncthreads();
    }

#pragma unroll
    for (int r = 0; r < 4; ++r) {
        float inv = 1.f / a_l[r];
        long row = (long)b * CHUNK + qc * 64 + w * 16 + h4 * 4 + r;
#pragma unroll
        for (int dt = 0; dt < 4; ++dt)
            o_mat[row * Dm + head * DH + dt * 16 + m16] = __float2bfloat16(acc_o[dt][r] * inv);
    }
}

// ---------------- orchestration ----------------

extern "C" void kernel_launch(void* const* d_in, const int* in_sizes, int n_in,
                              void* d_out, int out_size, void* d_ws, size_t ws_size,
                              hipStream_t stream) {
    const float* x     = (const float*)d_in[0];
    const float* state = (const float*)d_in[1];
    const float* Wq    = (const float*)d_in[2];
    const float* Wk    = (const float*)d_in[3];
    const float* Wv    = (const float*)d_in[4];
    const float* Wo    = (const float*)d_in[5];
    const float* bo    = (const float*)d_in[6];
    const float* lag   = (const float*)d_in[7];
    const float* lab   = (const float*)d_in[8];
    const float* lfg   = (const float*)d_in[9];
    const float* lfb   = (const float*)d_in[10];
    const float* W1    = (const float*)d_in[11];
    const float* b1    = (const float*)d_in[12];
    const float* W2    = (const float*)d_in[13];
    const float* b2    = (const float*)d_in[14];
    const float* Wsp   = (const float*)d_in[15];
    const float* bsp   = (const float*)d_in[16];
    const float* Wsi   = (const float*)d_in[17];
    const float* bsi   = (const float*)d_in[18];
    const float* gtok  = (const float*)d_in[19];

    float* out = (float*)d_out;
    char*  wsb = (char*)d_ws;

    // QKV hoist group size: all 16 steps if workspace allows (~110MB), else 4
    const long stepQ = 4L * TC * 1536;                 // bf16 elems per step slot
    const int G = (ws_size >= (size_t)115000000) ? 16 : 4;

    // workspace layout (bytes)
    bf16* wqkv   = (bf16*)(wsb);                      // 1536x1024   3,145,728
    bf16* wo     = (bf16*)(wsb + 3145728);            // 1024x1024   2,097,152
    bf16* w1     = (bf16*)(wsb + 5242880);            // 4096x1024   8,388,608
    bf16* w2     = (bf16*)(wsb + 13631488);           // 1024x4096   8,388,608
    bf16* Wfused = (bf16*)(wsb + 22020096);           // 1536x128      393,216
    bf16* WsiT   = (bf16*)(wsb + 22413312);           // 128x1024      262,144
    float* bfused= (float*)(wsb + 22675456);          // 1536            6,144
    float* st    = (float*)(wsb + 22681600);          // 512             2,048
    bf16* qkvg   = (bf16*)(wsb + 22683648);           // G slots x 3,244,032 B
    char* R2     = wsb + 22683648 + (size_t)G * 3244032;
    // R2: lnxg (G*1056*1024*2 B, setup-transient) ∪ loop {u, part, scrB}
    bf16* lnxg   = (bf16*)R2;
    bf16* u      = (bf16*)R2;                          // 1024x4096 bf16 = 8,388,608
    float* part  = (float*)(R2 + 8388608);             // 2x1024x1024 f32 = 8,388,608
    char* scrB   = R2 + 16777216;                      // o_mat ∪ t_ln ∪ colp (2,097,152)
    bf16* o_mat  = (bf16*)scrB;
    bf16* t_ln   = (bf16*)scrB;
    float* colp  = (float*)scrB;                       // 4x32x1024 f32 = 512KB
    // G=16 total ≈ 109.2MB ; G=4 total ≈ 54.5MB

    // ---- setup ----
    vcopy_k<<<1, 512, 0, stream>>>(state, st, 512);
    cvt_bf16_k<<<1024, 256, 0, stream>>>(Wq, wqkv,            262144);
    cvt_bf16_k<<< 256, 256, 0, stream>>>(Wk, wqkv + 1048576,   65536);
    cvt_bf16_k<<< 256, 256, 0, stream>>>(Wv, wqkv + 1310720,   65536);
    cvt_bf16_k<<<1024, 256, 0, stream>>>(Wo, wo,              262144);
    cvt_bf16_k<<<4096, 256, 0, stream>>>(W1, w1,             1048576);
    cvt_bf16_k<<<4096, 256, 0, stream>>>(W2, w2,             1048576);
    wsiT_k<<<512, 256, 0, stream>>>(Wsi, WsiT);
    // Wfused = wqkv @ WsiT^T : M=1536, N=128, K=1024
    gemm64<64><<<dim3(2, 24, 1), 256, 0, stream>>>(
        wqkv, WsiT, 1536, 128, 1024, 1024,
        Wfused, 128, nullptr, 0, nullptr, 0L);
    bfused_k<<<24, 64, 0, stream>>>(wqkv, bsi, bfused);

    for (int s = 0; s < NSTEP; ++s) {
        long roff = (long)s * CHUNK;
        if (s % G == 0) {
            // LN(x)+gtok rows for G steps, then one QKV GEMM: M = G*1056
            lng_k<<<dim3(G * 264, 4), 256, 0, stream>>>(x, gtok, lag, lab, lnxg, s);
            gemm64<128><<<dim3(12, G * 1056 / 64, 1), 256, 0, stream>>>(
                lnxg, wqkv, G * 1056, 1536, 1024, 1024,
                qkvg, 1536, nullptr, 0, nullptr, 0L);
        }
        const bf16* qkv_s = qkvg + (long)(s % G) * stepQ;
        // attention with in-block sib correction (reads st directly)
        attn_mfma_k<<<dim3(4, 16, 4), 256, 0, stream>>>(qkv_s, st, Wfused, bfused, o_mat);
        // Wo split-K (KS=2), BN=64 -> part; fused reduce(+bo,+x) + FFN LN
        gemm64<64><<<dim3(16, 16, 2), 256, 0, stream>>>(
            o_mat, wo, Bn * CHUNK, 1024, 1024, 512,
            nullptr, 0, nullptr, 0, part, 1048576L);
        reduce_ln_k<<<1024, 256, 0, stream>>>(part, bo, x, out, roff, lfg, lfb, t_ln);
        // FFN1 + gelu -> u bf16
        gemm64<128><<<dim3(32, 16, 1), 256, 0, stream>>>(
            t_ln, w1, Bn * CHUNK, 4096, 1024, 1024,
            u, 4096, b1, 1, nullptr, 0L);
        // FFN2 split-K (KS=2), BN=64 -> part; fused reduce(+b2,+c_pre) + column partials
        gemm64<64><<<dim3(16, 16, 2), 256, 0, stream>>>(
            u, w2, Bn * CHUNK, 1024, 4096, 2048,
            nullptr, 0, nullptr, 0, part, 1048576L);
        reduce_colpart_k<<<dim3(4, 32), 256, 0, stream>>>(part, b2, out, roff, colp);
        // state update (wide grid)
        state_update_k<<<dim3(4, 32), 256, 0, stream>>>(colp, Wsp, bsp, st);
    }
    vcopy_k<<<1, 512, 0, stream>>>(st, out + (long)Bn * Tn * Dm, 512);
}